// Round 18
// baseline (381.643 us; speedup 1.0000x reference)
//
#include <hip/hip_runtime.h>
#include <hip/hip_bf16.h>
#include <math.h>

typedef __bf16 bf16x8 __attribute__((ext_vector_type(8)));
typedef __bf16 bf16x4 __attribute__((ext_vector_type(4)));
typedef float f32x4 __attribute__((ext_vector_type(4)));
typedef unsigned int u32x2 __attribute__((ext_vector_type(2)));

__device__ __forceinline__ f32x4 mfma16(bf16x8 a, bf16x8 b, f32x4 c) {
  return __builtin_amdgcn_mfma_f32_16x16x32_bf16(a, b, c, 0, 0, 0);
}

// fast tanh-form GELU via native exp2 (R13, verified)
__device__ __forceinline__ float gelu_f(float v) {
  float x2 = v * v;
  float u = v * __builtin_fmaf(0.044715f, x2, 1.0f);
  float z = __builtin_amdgcn_exp2f(2.302101862f * u);
  float r = __builtin_amdgcn_rcpf(z + 1.0f);
  return __builtin_fmaf(-v, r, v);
}

__device__ __forceinline__ void async16(const void* g, void* l) {
  __builtin_amdgcn_global_load_lds((const __attribute__((address_space(1))) unsigned int*)g,
                                   (__attribute__((address_space(3))) unsigned int*)l, 16, 0, 0);
}

__device__ __forceinline__ unsigned lds_off(const void* p) {
  return (unsigned)(unsigned long long)(const __attribute__((address_space(3))) void*)p;
}

// ---- tiled transpose + bf16 convert: Wt[n][k] = (bf16) W[k][n];  W is K x N row-major.
__global__ __launch_bounds__(256) void wprep_kernel(const float* __restrict__ W, __bf16* __restrict__ Wt,
                                                    int K, int N) {
  __shared__ __bf16 tile[64][65];
  const int tn0 = blockIdx.x * 64, tk0 = blockIdx.y * 64;
  const int tr = threadIdx.x >> 4, tc = (threadIdx.x & 15) * 4;
#pragma unroll
  for (int p = 0; p < 4; ++p) {
    int r = p * 16 + tr;
    float4 v = *(const float4*)&W[(long)(tk0 + r) * N + tn0 + tc];
    tile[tc + 0][r] = (__bf16)v.x;
    tile[tc + 1][r] = (__bf16)v.y;
    tile[tc + 2][r] = (__bf16)v.z;
    tile[tc + 3][r] = (__bf16)v.w;
  }
  __syncthreads();
#pragma unroll
  for (int p = 0; p < 4; ++p) {
    int n = p * 16 + tr;
    bf16x4 o;
    o[0] = tile[n][tc]; o[1] = tile[n][tc + 1]; o[2] = tile[n][tc + 2]; o[3] = tile[n][tc + 3];
    *(bf16x4*)&Wt[(long)(tn0 + n) * K + tk0 + tc] = o;
  }
}

__global__ void bias_cat_kernel(const float* __restrict__ bq, const float* __restrict__ bk,
                                const float* __restrict__ bv, float* __restrict__ o) {
  int i = blockIdx.x * 256 + threadIdx.x;
  if (i >= 2304) return;
  o[i] = (i < 768) ? bq[i] : (i < 1536) ? bk[i - 768] : bv[i - 1536];
}

// ---- layernorm: fp32 in (rows x 768), bf16 out. One block (256 thr) per row.
__global__ __launch_bounds__(256) void ln_kernel(const float* __restrict__ x, const float* __restrict__ g,
                                                 const float* __restrict__ b, __bf16* __restrict__ out) {
  int row = blockIdx.x;
  const float* xr = x + (long)row * 768;
  float v0 = xr[threadIdx.x], v1 = xr[threadIdx.x + 256], v2 = xr[threadIdx.x + 512];
  float s = v0 + v1 + v2, s2 = v0 * v0 + v1 * v1 + v2 * v2;
#pragma unroll
  for (int m = 1; m < 64; m <<= 1) { s += __shfl_xor(s, m); s2 += __shfl_xor(s2, m); }
  __shared__ float ws1[4], ws2[4];
  int wv = threadIdx.x >> 6;
  if ((threadIdx.x & 63) == 0) { ws1[wv] = s; ws2[wv] = s2; }
  __syncthreads();
  s = ws1[0] + ws1[1] + ws1[2] + ws1[3];
  s2 = ws2[0] + ws2[1] + ws2[2] + ws2[3];
  float mu = s * (1.0f / 768.0f);
  float var = s2 * (1.0f / 768.0f) - mu * mu;
  float rstd = rsqrtf(var + 1e-5f);
  __bf16* orow = out + (long)row * 768;
  orow[threadIdx.x]       = (__bf16)((v0 - mu) * rstd * g[threadIdx.x]       + b[threadIdx.x]);
  orow[threadIdx.x + 256] = (__bf16)((v1 - mu) * rstd * g[threadIdx.x + 256] + b[threadIdx.x + 256]);
  orow[threadIdx.x + 512] = (__bf16)((v2 - mu) * rstd * g[threadIdx.x + 512] + b[threadIdx.x + 512]);
}

// ---- layernorm, bf16 input variant (for x2).
__global__ __launch_bounds__(256) void ln_b_kernel(const __bf16* __restrict__ x, const float* __restrict__ g,
                                                   const float* __restrict__ b, __bf16* __restrict__ out) {
  int row = blockIdx.x;
  const __bf16* xr = x + (long)row * 768;
  float v0 = (float)xr[threadIdx.x], v1 = (float)xr[threadIdx.x + 256], v2 = (float)xr[threadIdx.x + 512];
  float s = v0 + v1 + v2, s2 = v0 * v0 + v1 * v1 + v2 * v2;
#pragma unroll
  for (int m = 1; m < 64; m <<= 1) { s += __shfl_xor(s, m); s2 += __shfl_xor(s2, m); }
  __shared__ float ws1[4], ws2[4];
  int wv = threadIdx.x >> 6;
  if ((threadIdx.x & 63) == 0) { ws1[wv] = s; ws2[wv] = s2; }
  __syncthreads();
  s = ws1[0] + ws1[1] + ws1[2] + ws1[3];
  s2 = ws2[0] + ws2[1] + ws2[2] + ws2[3];
  float mu = s * (1.0f / 768.0f);
  float var = s2 * (1.0f / 768.0f) - mu * mu;
  float rstd = rsqrtf(var + 1e-5f);
  __bf16* orow = out + (long)row * 768;
  orow[threadIdx.x]       = (__bf16)((v0 - mu) * rstd * g[threadIdx.x]       + b[threadIdx.x]);
  orow[threadIdx.x + 256] = (__bf16)((v1 - mu) * rstd * g[threadIdx.x + 256] + b[threadIdx.x + 256]);
  orow[threadIdx.x + 512] = (__bf16)((v2 - mu) * rstd * g[threadIdx.x + 512] + b[threadIdx.x + 512]);
}

// ---- GEMM: m103 structure (R12/R14/R16-verified). 128x128, BK=64, 4 waves, 32KB LDS, (256,3).
// VGPR=80, zero spill. Larger tiles (128x192) spill at this occupancy (R15) — do not enlarge.
// EPI: 0 = bf16 out; 1 = gelu -> bf16 out; 3 = +fp32 res -> bf16 out; 4 = +bf16 res -> fp32 out.
template <int EPI>
__global__ __launch_bounds__(256, 3) void gemm_kernel(const __bf16* __restrict__ A, const __bf16* __restrict__ Wt,
                                                      const float* __restrict__ bias, const float* __restrict__ resf,
                                                      const __bf16* __restrict__ resb,
                                                      float* __restrict__ outf, __bf16* __restrict__ outb,
                                                      int M, int N, int K) {
  __shared__ __align__(16) __bf16 As[8192];
  __shared__ __align__(16) __bf16 Bs[8192];
  const int tid = threadIdx.x, lane = tid & 63, w = tid >> 6;
  const int wm = w >> 1, wn = w & 1, lr = lane & 15, lh = lane >> 4;
  const int gx = gridDim.x, gy = gridDim.y;
  int id = blockIdx.x + gx * blockIdx.y;
  int xcd = id & 7, slot = id >> 3;
  int by = xcd * (gy >> 3) + slot / gx;
  int bx = slot % gx;
  const int m0 = by * 128, n0 = bx * 128;
  const int nt = K >> 6;
  int srow[4], scol[4];
#pragma unroll
  for (int l = 0; l < 4; ++l) {
    int c = l * 256 + tid;
    srow[l] = c >> 3;
    scol[l] = ((c & 7) ^ ((c >> 3) & 7)) * 8;
  }
  const __bf16* Ag = A + (long)m0 * K;
  const __bf16* Bg = Wt + (long)n0 * K;

  f32x4 acc[4][4] = {};
  for (int t = 0; t < nt; ++t) {
    const int kb = t << 6;
    __syncthreads();
#pragma unroll
    for (int l = 0; l < 4; ++l) {
      async16(Ag + (long)srow[l] * K + kb + scol[l], &As[l * 2048 + w * 512]);
      async16(Bg + (long)srow[l] * K + kb + scol[l], &Bs[l * 2048 + w * 512]);
    }
    __syncthreads();
    bf16x8 af[4][2], bfr[4][2];
#pragma unroll
    for (int m4 = 0; m4 < 4; ++m4) {
      int row = wm * 64 + m4 * 16 + lr;
#pragma unroll
      for (int kk = 0; kk < 2; ++kk)
        af[m4][kk] = *(const bf16x8*)&As[row * 64 + ((kk * 32 + lh * 8) ^ ((row & 7) << 3))];
    }
#pragma unroll
    for (int n = 0; n < 4; ++n) {
      int row = wn * 64 + n * 16 + lr;
#pragma unroll
      for (int kk = 0; kk < 2; ++kk)
        bfr[n][kk] = *(const bf16x8*)&Bs[row * 64 + ((kk * 32 + lh * 8) ^ ((row & 7) << 3))];
    }
    __builtin_amdgcn_s_setprio(1);
#pragma unroll
    for (int m4 = 0; m4 < 4; ++m4)
#pragma unroll
      for (int n = 0; n < 4; ++n) {
        acc[m4][n] = mfma16(af[m4][0], bfr[n][0], acc[m4][n]);
        acc[m4][n] = mfma16(af[m4][1], bfr[n][1], acc[m4][n]);
      }
    __builtin_amdgcn_s_setprio(0);
  }

#pragma unroll
  for (int m = 0; m < 4; ++m)
#pragma unroll
    for (int n = 0; n < 4; ++n) {
      int col = n0 + wn * 64 + n * 16 + lr;
      float bc = bias[col];
#pragma unroll
      for (int j = 0; j < 4; ++j) {
        int row = m0 + wm * 64 + m * 16 + lh * 4 + j;
        float v = acc[m][n][j] + bc;
        if (EPI == 1) v = gelu_f(v);
        if (EPI == 3) outb[(long)row * N + col] = (__bf16)(v + resf[(long)row * N + col]);
        else if (EPI == 4) outf[(long)row * N + col] = v + (float)resb[(long)row * N + col];
        else outb[(long)row * N + col] = (__bf16)v;
      }
    }
}

// ---- flash attention on fused qkv buffer (rows x 2304).
// No-max softmax; P^T subtiled LDS with cvt_pk writes + tr-reads.
// R18: K/Vt double-buffered -> ONE barrier per tile; counted lgkmcnt(15) (4-bit field max)
// retires the 9 oldest DS ops = all 8 P-writes + 1 Vt read -> write->tr-read ordering holds
// while 15 Vt reads stay in flight. Per-wave lgkmcnt(0) before the barrier (R12 discipline).
__global__ __launch_bounds__(256) void attn_kernel(const __bf16* __restrict__ qkv, __bf16* __restrict__ o) {
  __shared__ __bf16 K_lds[2][64][72];
  __shared__ __align__(16) unsigned char Vt[2][8448];
  __shared__ __align__(16) unsigned char Pt[4][4224];
  const int tid = threadIdx.x;
  const int lane = tid & 63, wv = tid >> 6;
  const int lr = lane & 15, lh = lane >> 4;
  const int hb = blockIdx.x, qt = blockIdx.y;
  const int h = hb % 12, bz = hb / 12;
  const int qrow0 = bz * 1024 + qt * 128 + wv * 32;
  const int hcol = h * 64;
  const __bf16* q = qkv + hcol;
  const __bf16* k = qkv + 768 + hcol;
  const __bf16* v = qkv + 1536 + hcol;
  const float QSC = 0.18033688011112042f;  // 0.125 * log2(e)
  bf16x8 aq[2][2];
#pragma unroll
  for (int r = 0; r < 2; ++r)
#pragma unroll
    for (int kk = 0; kk < 2; ++kk) {
      bf16x8 t = *(const bf16x8*)(q + (long)(qrow0 + r * 16 + lr) * 2304 + kk * 32 + lh * 8);
#pragma unroll
      for (int e = 0; e < 8; ++e) t[e] = (__bf16)((float)t[e] * QSC);
      aq[r][kk] = t;
    }
  bf16x8 ones;
#pragma unroll
  for (int e = 0; e < 8; ++e) ones[e] = (__bf16)1.0f;
  f32x4 o_fr[2][4] = {};
  float l_s[2][4];
#pragma unroll
  for (int r = 0; r < 2; ++r)
#pragma unroll
    for (int j = 0; j < 4; ++j) l_s[r][j] = 0.0f;
  const int r0 = tid >> 3, c0 = (tid & 7) * 8;
  const unsigned vt0 = lds_off(&Vt[0][0]) + (lane >> 4) * 1056 + (lane & 15) * 2;
  const int Tst = (r0 >> 2) * 4 + (c0 >> 4);
  const int vb = Tst * 128 + (r0 & 3) * 32 + (c0 & 15) * 2 + (Tst >> 3) * 32;
  const unsigned pwb = lds_off(&Pt[wv][0]) + (lr >> 2) * 256 + (lr & 3) * 32 + lh * 8;
  const unsigned prb = lds_off(&Pt[wv][0]) + lh * 512 + (lh >> 1) * 32 + lr * 2;

  // pointer-incremented staging sources (advance 64 rows per tile)
  const __bf16* kp[2];
  const __bf16* vp[2];
#pragma unroll
  for (int p = 0; p < 2; ++p) {
    long gr = (long)(bz * 1024 + p * 32 + r0) * 2304 + c0;
    kp[p] = k + gr;
    vp[p] = v + gr;
  }
  bf16x8 rK[2], rV[2];
#pragma unroll
  for (int p = 0; p < 2; ++p) { rK[p] = *(const bf16x8*)kp[p]; rV[p] = *(const bf16x8*)vp[p]; }
#pragma unroll
  for (int p = 0; p < 2; ++p) {
    *(bf16x8*)&K_lds[0][p * 32 + r0][c0] = rK[p];
    *(bf16x8*)(&Vt[0][0] + vb + p * 4224) = rV[p];
  }
  __syncthreads();

  for (int t = 0; t < 16; ++t) {
    const int cur = t & 1, nxt = cur ^ 1;
    bf16x8 bk[4][2];
#pragma unroll
    for (int n = 0; n < 4; ++n)
#pragma unroll
      for (int kk = 0; kk < 2; ++kk)
        bk[n][kk] = *(const bf16x8*)&K_lds[cur][n * 16 + lr][kk * 32 + lh * 8];
    if (t < 15) {
#pragma unroll
      for (int p = 0; p < 2; ++p) {
        kp[p] += 64 * 2304; vp[p] += 64 * 2304;
        rK[p] = *(const bf16x8*)kp[p];
        rV[p] = *(const bf16x8*)vp[p];
      }
    }
    f32x4 sf[2][4];
    __builtin_amdgcn_s_setprio(1);
#pragma unroll
    for (int r = 0; r < 2; ++r)
#pragma unroll
      for (int n = 0; n < 4; ++n) {
        f32x4 s = {0.f, 0.f, 0.f, 0.f};
        s = mfma16(aq[r][0], bk[n][0], s);
        s = mfma16(aq[r][1], bk[n][1], s);
        sf[r][n] = s;
      }
    __builtin_amdgcn_s_setprio(0);
    // P^T writes first (8 x ds_write_b64) ...
#define PW(rr, nn)                                                                     \
    {                                                                                  \
      float e0 = __builtin_amdgcn_exp2f(sf[rr][nn][0]);                                \
      float e1 = __builtin_amdgcn_exp2f(sf[rr][nn][1]);                                \
      float e2 = __builtin_amdgcn_exp2f(sf[rr][nn][2]);                                \
      float e3 = __builtin_amdgcn_exp2f(sf[rr][nn][3]);                                \
      u32x2 d;                                                                         \
      asm("v_cvt_pk_bf16_f32 %0, %1, %2" : "=v"(d[0]) : "v"(e0), "v"(e1));             \
      asm("v_cvt_pk_bf16_f32 %0, %1, %2" : "=v"(d[1]) : "v"(e2), "v"(e3));             \
      asm volatile("ds_write_b64 %0, %1 offset:%2" ::"v"(pwb), "v"(d),                 \
                   "i"((nn)*1056 + (rr)*128) : "memory");                              \
    }
    PW(0, 0) PW(0, 1) PW(0, 2) PW(0, 3) PW(1, 0) PW(1, 1) PW(1, 2) PW(1, 3)
#undef PW
    // ... then the 16 Vt tr-reads (independent of P writes)
    u32x2 trv[4][2][2];
    {
      unsigned vtc = vt0 + (unsigned)cur * 8448u;
#pragma unroll
      for (int d0 = 0; d0 < 4; ++d0)
#pragma unroll
        for (int ks = 0; ks < 2; ++ks) {
          unsigned a = vtc + ks * 4224 + d0 * 128;
          asm volatile("ds_read_b64_tr_b16 %0, %1" : "=v"(trv[d0][ks][0]) : "v"(a));
          asm volatile("ds_read_b64_tr_b16 %0, %1 offset:512" : "=v"(trv[d0][ks][1]) : "v"(a));
        }
    }
    // counted wait (4-bit max 15): 9 oldest DS ops retired >= all 8 P writes
    asm volatile("s_waitcnt lgkmcnt(15)" ::: "memory");
    __builtin_amdgcn_sched_barrier(0);
    u32x2 trp[2][2][2];
#define PR(rr, kks)                                                                     \
    asm volatile("ds_read_b64_tr_b16 %0, %1 offset:%2"                                  \
                 : "=v"(trp[rr][kks][0]) : "v"(prb), "i"((rr)*128 + (kks)*2112));       \
    asm volatile("ds_read_b64_tr_b16 %0, %1 offset:%2"                                  \
                 : "=v"(trp[rr][kks][1]) : "v"(prb), "i"((rr)*128 + (kks)*2112 + 256));
    PR(0, 0) PR(0, 1) PR(1, 0) PR(1, 1)
#undef PR
    asm volatile("s_waitcnt lgkmcnt(0)" ::: "memory");
    __builtin_amdgcn_sched_barrier(0);
    // stage tile t+1 into the OTHER buffer (disjoint from current reads)
    if (t < 15) {
#pragma unroll
      for (int p = 0; p < 2; ++p) {
        *(bf16x8*)&K_lds[nxt][p * 32 + r0][c0] = rK[p];
        *(bf16x8*)(&Vt[nxt][0] + vb + p * 4224) = rV[p];
      }
    }
    bf16x8 ap[2][2];
#pragma unroll
    for (int r = 0; r < 2; ++r)
#pragma unroll
      for (int ks = 0; ks < 2; ++ks) {
        union { u32x2 u[2]; bf16x8 v8; } pu;
        pu.u[0] = trp[r][ks][0];
        pu.u[1] = trp[r][ks][1];
        ap[r][ks] = pu.v8;
      }
    __builtin_amdgcn_s_setprio(1);
#pragma unroll
    for (int r = 0; r < 2; ++r) {
      f32x4 ls = {0.f, 0.f, 0.f, 0.f};
      ls = mfma16(ap[r][0], ones, ls);
      ls = mfma16(ap[r][1], ones, ls);
#pragma unroll
      for (int j = 0; j < 4; ++j) l_s[r][j] += ls[j];
    }
#pragma unroll
    for (int d0 = 0; d0 < 4; ++d0) {
      union { u32x2 u[2]; bf16x8 v8; } b0, b1;
      b0.u[0] = trv[d0][0][0]; b0.u[1] = trv[d0][0][1];
      b1.u[0] = trv[d0][1][0]; b1.u[1] = trv[d0][1][1];
#pragma unroll
      for (int r = 0; r < 2; ++r) {
        o_fr[r][d0] = mfma16(ap[r][0], b0.v8, o_fr[r][d0]);
        o_fr[r][d0] = mfma16(ap[r][1], b1.v8, o_fr[r][d0]);
      }
    }
    __builtin_amdgcn_s_setprio(0);
    if (t < 15) __syncthreads();   // single barrier per tile: buf[nxt] visible for next iter
  }
#pragma unroll
  for (int r = 0; r < 2; ++r)
#pragma unroll
    for (int d = 0; d < 4; ++d)
#pragma unroll
      for (int j = 0; j < 4; ++j) {
        int row = qrow0 + r * 16 + lh * 4 + j;
        int col = hcol + d * 16 + lr;
        o[(long)row * 768 + col] = (__bf16)(o_fr[r][d][j] * (1.0f / l_s[r][j]));
      }
}

extern "C" void kernel_launch(void* const* d_in, const int* in_sizes, int n_in,
                              void* d_out, int out_size, void* d_ws, size_t ws_size,
                              hipStream_t stream) {
  const float* x    = (const float*)d_in[0];
  const float* ln1g = (const float*)d_in[1];
  const float* ln1b = (const float*)d_in[2];
  const float* wq   = (const float*)d_in[3];
  const float* bq   = (const float*)d_in[4];
  const float* wk   = (const float*)d_in[5];
  const float* bk   = (const float*)d_in[6];
  const float* wv   = (const float*)d_in[7];
  const float* bv   = (const float*)d_in[8];
  const float* wo   = (const float*)d_in[9];
  const float* bo   = (const float*)d_in[10];
  const float* ln2g = (const float*)d_in[11];
  const float* ln2b = (const float*)d_in[12];
  const float* w1   = (const float*)d_in[13];
  const float* b1   = (const float*)d_in[14];
  const float* w2   = (const float*)d_in[15];
  const float* b2   = (const float*)d_in[16];
  float* out = (float*)d_out;
  char* ws = (char*)d_ws;

  const long SD = 16384L * 768;
  const long SF = 16384L * 3072;

  __bf16* qkv = (__bf16*)(ws);                      // 16384 x 2304
  __bf16* f1  = (__bf16*)(ws);                      // aliases qkv (dead by FFN1)
  __bf16* hb  = (__bf16*)(ws + 2 * SF);             // LN1 out; later attn out
  __bf16* x2  = (__bf16*)(ws + 2 * SF + 2 * SD);    // bf16
  __bf16* h2  = (__bf16*)(ws + 2 * SF + 2 * SD + 4 * SD);
  __bf16* wtqkv = (__bf16*)(ws + 2 * SF + 2 * SD + 4 * SD + 2 * SD);  // 2304 x 768
  __bf16* wto = wtqkv + 2304L * 768;
  __bf16* wt1 = wto + 768L * 768;
  __bf16* wt2 = wt1 + 768L * 3072;
  float*  bqkv = (float*)(wt2 + 3072L * 768);

  wprep_kernel<<<dim3(12, 12), 256, 0, stream>>>(wq, wtqkv,               768, 768);
  wprep_kernel<<<dim3(12, 12), 256, 0, stream>>>(wk, wtqkv + 768L * 768,  768, 768);
  wprep_kernel<<<dim3(12, 12), 256, 0, stream>>>(wv, wtqkv + 1536L * 768, 768, 768);
  wprep_kernel<<<dim3(12, 12), 256, 0, stream>>>(wo, wto, 768, 768);
  wprep_kernel<<<dim3(48, 12), 256, 0, stream>>>(w1, wt1, 768, 3072);
  wprep_kernel<<<dim3(12, 48), 256, 0, stream>>>(w2, wt2, 3072, 768);
  bias_cat_kernel<<<9, 256, 0, stream>>>(bq, bk, bv, bqkv);

  ln_kernel<<<16384, 256, 0, stream>>>(x, ln1g, ln1b, hb);
  gemm_kernel<0><<<dim3(18, 128), 256, 0, stream>>>(hb, wtqkv, bqkv, nullptr, nullptr, nullptr, qkv, 16384, 2304, 768);
  attn_kernel<<<dim3(192, 8), 256, 0, stream>>>(qkv, hb);
  gemm_kernel<3><<<dim3(6, 128), 256, 0, stream>>>(hb, wto, bo, x, nullptr, nullptr, x2, 16384, 768, 768);
  ln_b_kernel<<<16384, 256, 0, stream>>>(x2, ln2g, ln2b, h2);
  gemm_kernel<1><<<dim3(24, 128), 256, 0, stream>>>(h2, wt1, b1, nullptr, nullptr, nullptr, f1, 16384, 3072, 768);
  gemm_kernel<4><<<dim3(6, 128), 256, 0, stream>>>(f1, wt2, b2, nullptr, x2, out, nullptr, 16384, 768, 3072);
}

// Round 19
// 370.248 us; speedup vs baseline: 1.0308x; 1.0308x over previous
//
#include <hip/hip_runtime.h>
#include <hip/hip_bf16.h>
#include <math.h>

typedef __bf16 bf16x8 __attribute__((ext_vector_type(8)));
typedef __bf16 bf16x4 __attribute__((ext_vector_type(4)));
typedef float f32x4 __attribute__((ext_vector_type(4)));
typedef unsigned int u32x2 __attribute__((ext_vector_type(2)));

__device__ __forceinline__ f32x4 mfma16(bf16x8 a, bf16x8 b, f32x4 c) {
  return __builtin_amdgcn_mfma_f32_16x16x32_bf16(a, b, c, 0, 0, 0);
}

// fast tanh-form GELU via native exp2 (R13, verified)
__device__ __forceinline__ float gelu_f(float v) {
  float x2 = v * v;
  float u = v * __builtin_fmaf(0.044715f, x2, 1.0f);
  float z = __builtin_amdgcn_exp2f(2.302101862f * u);
  float r = __builtin_amdgcn_rcpf(z + 1.0f);
  return __builtin_fmaf(-v, r, v);
}

__device__ __forceinline__ void async16(const void* g, void* l) {
  __builtin_amdgcn_global_load_lds((const __attribute__((address_space(1))) unsigned int*)g,
                                   (__attribute__((address_space(3))) unsigned int*)l, 16, 0, 0);
}

__device__ __forceinline__ unsigned lds_off(const void* p) {
  return (unsigned)(unsigned long long)(const __attribute__((address_space(3))) void*)p;
}

// ---- tiled transpose + bf16 convert: Wt[n][k] = (bf16) W[k][n];  W is K x N row-major.
__global__ __launch_bounds__(256) void wprep_kernel(const float* __restrict__ W, __bf16* __restrict__ Wt,
                                                    int K, int N) {
  __shared__ __bf16 tile[64][65];
  const int tn0 = blockIdx.x * 64, tk0 = blockIdx.y * 64;
  const int tr = threadIdx.x >> 4, tc = (threadIdx.x & 15) * 4;
#pragma unroll
  for (int p = 0; p < 4; ++p) {
    int r = p * 16 + tr;
    float4 v = *(const float4*)&W[(long)(tk0 + r) * N + tn0 + tc];
    tile[tc + 0][r] = (__bf16)v.x;
    tile[tc + 1][r] = (__bf16)v.y;
    tile[tc + 2][r] = (__bf16)v.z;
    tile[tc + 3][r] = (__bf16)v.w;
  }
  __syncthreads();
#pragma unroll
  for (int p = 0; p < 4; ++p) {
    int n = p * 16 + tr;
    bf16x4 o;
    o[0] = tile[n][tc]; o[1] = tile[n][tc + 1]; o[2] = tile[n][tc + 2]; o[3] = tile[n][tc + 3];
    *(bf16x4*)&Wt[(long)(tn0 + n) * K + tk0 + tc] = o;
  }
}

__global__ void bias_cat_kernel(const float* __restrict__ bq, const float* __restrict__ bk,
                                const float* __restrict__ bv, float* __restrict__ o) {
  int i = blockIdx.x * 256 + threadIdx.x;
  if (i >= 2304) return;
  o[i] = (i < 768) ? bq[i] : (i < 1536) ? bk[i - 768] : bv[i - 1536];
}

// ---- layernorm: fp32 in (rows x 768), bf16 out. One block (256 thr) per row.
__global__ __launch_bounds__(256) void ln_kernel(const float* __restrict__ x, const float* __restrict__ g,
                                                 const float* __restrict__ b, __bf16* __restrict__ out) {
  int row = blockIdx.x;
  const float* xr = x + (long)row * 768;
  float v0 = xr[threadIdx.x], v1 = xr[threadIdx.x + 256], v2 = xr[threadIdx.x + 512];
  float s = v0 + v1 + v2, s2 = v0 * v0 + v1 * v1 + v2 * v2;
#pragma unroll
  for (int m = 1; m < 64; m <<= 1) { s += __shfl_xor(s, m); s2 += __shfl_xor(s2, m); }
  __shared__ float ws1[4], ws2[4];
  int wv = threadIdx.x >> 6;
  if ((threadIdx.x & 63) == 0) { ws1[wv] = s; ws2[wv] = s2; }
  __syncthreads();
  s = ws1[0] + ws1[1] + ws1[2] + ws1[3];
  s2 = ws2[0] + ws2[1] + ws2[2] + ws2[3];
  float mu = s * (1.0f / 768.0f);
  float var = s2 * (1.0f / 768.0f) - mu * mu;
  float rstd = rsqrtf(var + 1e-5f);
  __bf16* orow = out + (long)row * 768;
  orow[threadIdx.x]       = (__bf16)((v0 - mu) * rstd * g[threadIdx.x]       + b[threadIdx.x]);
  orow[threadIdx.x + 256] = (__bf16)((v1 - mu) * rstd * g[threadIdx.x + 256] + b[threadIdx.x + 256]);
  orow[threadIdx.x + 512] = (__bf16)((v2 - mu) * rstd * g[threadIdx.x + 512] + b[threadIdx.x + 512]);
}

// ---- layernorm, bf16 input variant (for x2).
__global__ __launch_bounds__(256) void ln_b_kernel(const __bf16* __restrict__ x, const float* __restrict__ g,
                                                   const float* __restrict__ b, __bf16* __restrict__ out) {
  int row = blockIdx.x;
  const __bf16* xr = x + (long)row * 768;
  float v0 = (float)xr[threadIdx.x], v1 = (float)xr[threadIdx.x + 256], v2 = (float)xr[threadIdx.x + 512];
  float s = v0 + v1 + v2, s2 = v0 * v0 + v1 * v1 + v2 * v2;
#pragma unroll
  for (int m = 1; m < 64; m <<= 1) { s += __shfl_xor(s, m); s2 += __shfl_xor(s2, m); }
  __shared__ float ws1[4], ws2[4];
  int wv = threadIdx.x >> 6;
  if ((threadIdx.x & 63) == 0) { ws1[wv] = s; ws2[wv] = s2; }
  __syncthreads();
  s = ws1[0] + ws1[1] + ws1[2] + ws1[3];
  s2 = ws2[0] + ws2[1] + ws2[2] + ws2[3];
  float mu = s * (1.0f / 768.0f);
  float var = s2 * (1.0f / 768.0f) - mu * mu;
  float rstd = rsqrtf(var + 1e-5f);
  __bf16* orow = out + (long)row * 768;
  orow[threadIdx.x]       = (__bf16)((v0 - mu) * rstd * g[threadIdx.x]       + b[threadIdx.x]);
  orow[threadIdx.x + 256] = (__bf16)((v1 - mu) * rstd * g[threadIdx.x + 256] + b[threadIdx.x + 256]);
  orow[threadIdx.x + 512] = (__bf16)((v2 - mu) * rstd * g[threadIdx.x + 512] + b[threadIdx.x + 512]);
}

// ---- GEMM: m103 structure (R12/R14/R16-verified). 128x128, BK=64, 4 waves, 32KB LDS, (256,3).
// VGPR=80, zero spill. Larger tiles (128x192) spill at this occupancy (R15) — do not enlarge.
// EPI: 0 = bf16 out; 1 = gelu -> bf16 out; 3 = +fp32 res -> bf16 out; 4 = +bf16 res -> fp32 out.
template <int EPI>
__global__ __launch_bounds__(256, 3) void gemm_kernel(const __bf16* __restrict__ A, const __bf16* __restrict__ Wt,
                                                      const float* __restrict__ bias, const float* __restrict__ resf,
                                                      const __bf16* __restrict__ resb,
                                                      float* __restrict__ outf, __bf16* __restrict__ outb,
                                                      int M, int N, int K) {
  __shared__ __align__(16) __bf16 As[8192];
  __shared__ __align__(16) __bf16 Bs[8192];
  const int tid = threadIdx.x, lane = tid & 63, w = tid >> 6;
  const int wm = w >> 1, wn = w & 1, lr = lane & 15, lh = lane >> 4;
  const int gx = gridDim.x, gy = gridDim.y;
  int id = blockIdx.x + gx * blockIdx.y;
  int xcd = id & 7, slot = id >> 3;
  int by = xcd * (gy >> 3) + slot / gx;
  int bx = slot % gx;
  const int m0 = by * 128, n0 = bx * 128;
  const int nt = K >> 6;
  int srow[4], scol[4];
#pragma unroll
  for (int l = 0; l < 4; ++l) {
    int c = l * 256 + tid;
    srow[l] = c >> 3;
    scol[l] = ((c & 7) ^ ((c >> 3) & 7)) * 8;
  }
  const __bf16* Ag = A + (long)m0 * K;
  const __bf16* Bg = Wt + (long)n0 * K;

  f32x4 acc[4][4] = {};
  for (int t = 0; t < nt; ++t) {
    const int kb = t << 6;
    __syncthreads();
#pragma unroll
    for (int l = 0; l < 4; ++l) {
      async16(Ag + (long)srow[l] * K + kb + scol[l], &As[l * 2048 + w * 512]);
      async16(Bg + (long)srow[l] * K + kb + scol[l], &Bs[l * 2048 + w * 512]);
    }
    __syncthreads();
    bf16x8 af[4][2], bfr[4][2];
#pragma unroll
    for (int m4 = 0; m4 < 4; ++m4) {
      int row = wm * 64 + m4 * 16 + lr;
#pragma unroll
      for (int kk = 0; kk < 2; ++kk)
        af[m4][kk] = *(const bf16x8*)&As[row * 64 + ((kk * 32 + lh * 8) ^ ((row & 7) << 3))];
    }
#pragma unroll
    for (int n = 0; n < 4; ++n) {
      int row = wn * 64 + n * 16 + lr;
#pragma unroll
      for (int kk = 0; kk < 2; ++kk)
        bfr[n][kk] = *(const bf16x8*)&Bs[row * 64 + ((kk * 32 + lh * 8) ^ ((row & 7) << 3))];
    }
    __builtin_amdgcn_s_setprio(1);
#pragma unroll
    for (int m4 = 0; m4 < 4; ++m4)
#pragma unroll
      for (int n = 0; n < 4; ++n) {
        acc[m4][n] = mfma16(af[m4][0], bfr[n][0], acc[m4][n]);
        acc[m4][n] = mfma16(af[m4][1], bfr[n][1], acc[m4][n]);
      }
    __builtin_amdgcn_s_setprio(0);
  }

#pragma unroll
  for (int m = 0; m < 4; ++m)
#pragma unroll
    for (int n = 0; n < 4; ++n) {
      int col = n0 + wn * 64 + n * 16 + lr;
      float bc = bias[col];
#pragma unroll
      for (int j = 0; j < 4; ++j) {
        int row = m0 + wm * 64 + m * 16 + lh * 4 + j;
        float v = acc[m][n][j] + bc;
        if (EPI == 1) v = gelu_f(v);
        if (EPI == 3) outb[(long)row * N + col] = (__bf16)(v + resf[(long)row * N + col]);
        else if (EPI == 4) outf[(long)row * N + col] = v + (float)resb[(long)row * N + col];
        else outb[(long)row * N + col] = (__bf16)v;
      }
    }
}

// ---- flash attention on fused qkv buffer (rows x 2304).
// R19: 8 waves / 256 q-rows per block (grid 192x4, 512 thr) — K/V staged ONCE for 8 waves
// (per-thread staging halves; total K/V HBM fetch halves); ~24 waves/CU resident.
// R16-proven 2-barrier scheme; counted lgkmcnt(15) retires all 8 P-writes before Pt reads.
__global__ __launch_bounds__(512) void attn_kernel(const __bf16* __restrict__ qkv, __bf16* __restrict__ o) {
  __shared__ __bf16 K_lds[64][72];
  __shared__ __align__(16) unsigned char Vt[8448];
  __shared__ __align__(16) unsigned char Pt[8][4224];
  const int tid = threadIdx.x;
  const int lane = tid & 63, wv = tid >> 6;
  const int lr = lane & 15, lh = lane >> 4;
  const int hb = blockIdx.x, qt = blockIdx.y;
  const int h = hb % 12, bz = hb / 12;
  const int qrow0 = bz * 1024 + qt * 256 + wv * 32;
  const int hcol = h * 64;
  const __bf16* q = qkv + hcol;
  const __bf16* k = qkv + 768 + hcol;
  const __bf16* v = qkv + 1536 + hcol;
  const float QSC = 0.18033688011112042f;  // 0.125 * log2(e)
  bf16x8 aq[2][2];
#pragma unroll
  for (int r = 0; r < 2; ++r)
#pragma unroll
    for (int kk = 0; kk < 2; ++kk) {
      bf16x8 t = *(const bf16x8*)(q + (long)(qrow0 + r * 16 + lr) * 2304 + kk * 32 + lh * 8);
#pragma unroll
      for (int e = 0; e < 8; ++e) t[e] = (__bf16)((float)t[e] * QSC);
      aq[r][kk] = t;
    }
  bf16x8 ones;
#pragma unroll
  for (int e = 0; e < 8; ++e) ones[e] = (__bf16)1.0f;
  f32x4 o_fr[2][4] = {};
  float l_s[2][4];
#pragma unroll
  for (int r = 0; r < 2; ++r)
#pragma unroll
    for (int j = 0; j < 4; ++j) l_s[r][j] = 0.0f;
  const int r0 = tid >> 3, c0 = (tid & 7) * 8;   // r0 in [0,64) with 512 threads
  const unsigned vt0 = lds_off(Vt) + (lane >> 4) * 1056 + (lane & 15) * 2;
  const int Tst = (r0 >> 2) * 4 + (c0 >> 4);
  const int vb = Tst * 128 + (r0 & 3) * 32 + (c0 & 15) * 2 + (Tst >> 3) * 32;
  const unsigned pwb = lds_off(&Pt[wv][0]) + (lr >> 2) * 256 + (lr & 3) * 32 + lh * 8;
  const unsigned prb = lds_off(&Pt[wv][0]) + lh * 512 + (lh >> 1) * 32 + lr * 2;

  // pointer-incremented staging sources (one K + one V chunk per thread per tile)
  const __bf16* kp = k + (long)(bz * 1024 + r0) * 2304 + c0;
  const __bf16* vp = v + (long)(bz * 1024 + r0) * 2304 + c0;
  bf16x8 rK = *(const bf16x8*)kp;
  bf16x8 rV = *(const bf16x8*)vp;
  *(bf16x8*)&K_lds[r0][c0] = rK;
  *(bf16x8*)(Vt + vb) = rV;
  __syncthreads();

  for (int t = 0; t < 16; ++t) {
    bf16x8 bk[4][2];
#pragma unroll
    for (int n = 0; n < 4; ++n)
#pragma unroll
      for (int kk = 0; kk < 2; ++kk)
        bk[n][kk] = *(const bf16x8*)&K_lds[n * 16 + lr][kk * 32 + lh * 8];
    if (t < 15) {
      kp += 64 * 2304; vp += 64 * 2304;
      rK = *(const bf16x8*)kp;
      rV = *(const bf16x8*)vp;
    }
    f32x4 sf[2][4];
    __builtin_amdgcn_s_setprio(1);
#pragma unroll
    for (int r = 0; r < 2; ++r)
#pragma unroll
      for (int n = 0; n < 4; ++n) {
        f32x4 s = {0.f, 0.f, 0.f, 0.f};
        s = mfma16(aq[r][0], bk[n][0], s);
        s = mfma16(aq[r][1], bk[n][1], s);
        sf[r][n] = s;
      }
    __builtin_amdgcn_s_setprio(0);
    // P^T writes (8 x ds_write_b64) ...
#define PW(rr, nn)                                                                     \
    {                                                                                  \
      float e0 = __builtin_amdgcn_exp2f(sf[rr][nn][0]);                                \
      float e1 = __builtin_amdgcn_exp2f(sf[rr][nn][1]);                                \
      float e2 = __builtin_amdgcn_exp2f(sf[rr][nn][2]);                                \
      float e3 = __builtin_amdgcn_exp2f(sf[rr][nn][3]);                                \
      u32x2 d;                                                                         \
      asm("v_cvt_pk_bf16_f32 %0, %1, %2" : "=v"(d[0]) : "v"(e0), "v"(e1));             \
      asm("v_cvt_pk_bf16_f32 %0, %1, %2" : "=v"(d[1]) : "v"(e2), "v"(e3));             \
      asm volatile("ds_write_b64 %0, %1 offset:%2" ::"v"(pwb), "v"(d),                 \
                   "i"((nn)*1056 + (rr)*128) : "memory");                              \
    }
    PW(0, 0) PW(0, 1) PW(0, 2) PW(0, 3) PW(1, 0) PW(1, 1) PW(1, 2) PW(1, 3)
#undef PW
    // ... then the 16 Vt tr-reads (independent of P writes)
    u32x2 trv[4][2][2];
#pragma unroll
    for (int d0 = 0; d0 < 4; ++d0)
#pragma unroll
      for (int ks = 0; ks < 2; ++ks) {
        unsigned a = vt0 + ks * 4224 + d0 * 128;
        asm volatile("ds_read_b64_tr_b16 %0, %1" : "=v"(trv[d0][ks][0]) : "v"(a));
        asm volatile("ds_read_b64_tr_b16 %0, %1 offset:512" : "=v"(trv[d0][ks][1]) : "v"(a));
      }
    // counted wait (4-bit max 15): 9 oldest DS ops retired >= all 8 P writes
    asm volatile("s_waitcnt lgkmcnt(15)" ::: "memory");
    __builtin_amdgcn_sched_barrier(0);
    u32x2 trp[2][2][2];
#define PR(rr, kks)                                                                     \
    asm volatile("ds_read_b64_tr_b16 %0, %1 offset:%2"                                  \
                 : "=v"(trp[rr][kks][0]) : "v"(prb), "i"((rr)*128 + (kks)*2112));       \
    asm volatile("ds_read_b64_tr_b16 %0, %1 offset:%2"                                  \
                 : "=v"(trp[rr][kks][1]) : "v"(prb), "i"((rr)*128 + (kks)*2112 + 256));
    PR(0, 0) PR(0, 1) PR(1, 0) PR(1, 1)
#undef PR
    asm volatile("s_waitcnt lgkmcnt(0)" ::: "memory");
    __builtin_amdgcn_sched_barrier(0);
    __syncthreads();                 // all waves done reading K_lds/Vt of tile t
    if (t < 15) {                    // stage t+1 under the PV MFMAs
      *(bf16x8*)&K_lds[r0][c0] = rK;
      *(bf16x8*)(Vt + vb) = rV;
    }
    bf16x8 ap[2][2];
#pragma unroll
    for (int r = 0; r < 2; ++r)
#pragma unroll
      for (int ks = 0; ks < 2; ++ks) {
        union { u32x2 u[2]; bf16x8 v8; } pu;
        pu.u[0] = trp[r][ks][0];
        pu.u[1] = trp[r][ks][1];
        ap[r][ks] = pu.v8;
      }
    __builtin_amdgcn_s_setprio(1);
#pragma unroll
    for (int r = 0; r < 2; ++r) {
      f32x4 ls = {0.f, 0.f, 0.f, 0.f};
      ls = mfma16(ap[r][0], ones, ls);
      ls = mfma16(ap[r][1], ones, ls);
#pragma unroll
      for (int j = 0; j < 4; ++j) l_s[r][j] += ls[j];
    }
#pragma unroll
    for (int d0 = 0; d0 < 4; ++d0) {
      union { u32x2 u[2]; bf16x8 v8; } b0, b1;
      b0.u[0] = trv[d0][0][0]; b0.u[1] = trv[d0][0][1];
      b1.u[0] = trv[d0][1][0]; b1.u[1] = trv[d0][1][1];
#pragma unroll
      for (int r = 0; r < 2; ++r) {
        o_fr[r][d0] = mfma16(ap[r][0], b0.v8, o_fr[r][d0]);
        o_fr[r][d0] = mfma16(ap[r][1], b1.v8, o_fr[r][d0]);
      }
    }
    __builtin_amdgcn_s_setprio(0);
    if (t < 15) __syncthreads();     // staging writes visible before next tile's reads
  }
#pragma unroll
  for (int r = 0; r < 2; ++r)
#pragma unroll
    for (int d = 0; d < 4; ++d)
#pragma unroll
      for (int j = 0; j < 4; ++j) {
        int row = qrow0 + r * 16 + lh * 4 + j;
        int col = hcol + d * 16 + lr;
        o[(long)row * 768 + col] = (__bf16)(o_fr[r][d][j] * (1.0f / l_s[r][j]));
      }
}

extern "C" void kernel_launch(void* const* d_in, const int* in_sizes, int n_in,
                              void* d_out, int out_size, void* d_ws, size_t ws_size,
                              hipStream_t stream) {
  const float* x    = (const float*)d_in[0];
  const float* ln1g = (const float*)d_in[1];
  const float* ln1b = (const float*)d_in[2];
  const float* wq   = (const float*)d_in[3];
  const float* bq   = (const float*)d_in[4];
  const float* wk   = (const float*)d_in[5];
  const float* bk   = (const float*)d_in[6];
  const float* wv   = (const float*)d_in[7];
  const float* bv   = (const float*)d_in[8];
  const float* wo   = (const float*)d_in[9];
  const float* bo   = (const float*)d_in[10];
  const float* ln2g = (const float*)d_in[11];
  const float* ln2b = (const float*)d_in[12];
  const float* w1   = (const float*)d_in[13];
  const float* b1   = (const float*)d_in[14];
  const float* w2   = (const float*)d_in[15];
  const float* b2   = (const float*)d_in[16];
  float* out = (float*)d_out;
  char* ws = (char*)d_ws;

  const long SD = 16384L * 768;
  const long SF = 16384L * 3072;

  __bf16* qkv = (__bf16*)(ws);                      // 16384 x 2304
  __bf16* f1  = (__bf16*)(ws);                      // aliases qkv (dead by FFN1)
  __bf16* hb  = (__bf16*)(ws + 2 * SF);             // LN1 out; later attn out
  __bf16* x2  = (__bf16*)(ws + 2 * SF + 2 * SD);    // bf16
  __bf16* h2  = (__bf16*)(ws + 2 * SF + 2 * SD + 4 * SD);
  __bf16* wtqkv = (__bf16*)(ws + 2 * SF + 2 * SD + 4 * SD + 2 * SD);  // 2304 x 768
  __bf16* wto = wtqkv + 2304L * 768;
  __bf16* wt1 = wto + 768L * 768;
  __bf16* wt2 = wt1 + 768L * 3072;
  float*  bqkv = (float*)(wt2 + 3072L * 768);

  wprep_kernel<<<dim3(12, 12), 256, 0, stream>>>(wq, wtqkv,               768, 768);
  wprep_kernel<<<dim3(12, 12), 256, 0, stream>>>(wk, wtqkv + 768L * 768,  768, 768);
  wprep_kernel<<<dim3(12, 12), 256, 0, stream>>>(wv, wtqkv + 1536L * 768, 768, 768);
  wprep_kernel<<<dim3(12, 12), 256, 0, stream>>>(wo, wto, 768, 768);
  wprep_kernel<<<dim3(48, 12), 256, 0, stream>>>(w1, wt1, 768, 3072);
  wprep_kernel<<<dim3(12, 48), 256, 0, stream>>>(w2, wt2, 3072, 768);
  bias_cat_kernel<<<9, 256, 0, stream>>>(bq, bk, bv, bqkv);

  ln_kernel<<<16384, 256, 0, stream>>>(x, ln1g, ln1b, hb);
  gemm_kernel<0><<<dim3(18, 128), 256, 0, stream>>>(hb, wtqkv, bqkv, nullptr, nullptr, nullptr, qkv, 16384, 2304, 768);
  attn_kernel<<<dim3(192, 4), 512, 0, stream>>>(qkv, hb);
  gemm_kernel<3><<<dim3(6, 128), 256, 0, stream>>>(hb, wto, bo, x, nullptr, nullptr, x2, 16384, 768, 768);
  ln_b_kernel<<<16384, 256, 0, stream>>>(x2, ln2g, ln2b, h2);
  gemm_kernel<1><<<dim3(24, 128), 256, 0, stream>>>(h2, wt1, b1, nullptr, nullptr, nullptr, f1, 16384, 3072, 768);
  gemm_kernel<4><<<dim3(6, 128), 256, 0, stream>>>(f1, wt2, b2, nullptr, x2, out, nullptr, 16384, 768, 3072);
}

// Round 20
// 355.720 us; speedup vs baseline: 1.0729x; 1.0408x over previous
//
#include <hip/hip_runtime.h>
#include <hip/hip_bf16.h>
#include <math.h>

typedef __bf16 bf16x8 __attribute__((ext_vector_type(8)));
typedef __bf16 bf16x4 __attribute__((ext_vector_type(4)));
typedef float f32x4 __attribute__((ext_vector_type(4)));
typedef unsigned int u32x2 __attribute__((ext_vector_type(2)));

__device__ __forceinline__ f32x4 mfma16(bf16x8 a, bf16x8 b, f32x4 c) {
  return __builtin_amdgcn_mfma_f32_16x16x32_bf16(a, b, c, 0, 0, 0);
}

// fast tanh-form GELU via native exp2 (R13, verified)
__device__ __forceinline__ float gelu_f(float v) {
  float x2 = v * v;
  float u = v * __builtin_fmaf(0.044715f, x2, 1.0f);
  float z = __builtin_amdgcn_exp2f(2.302101862f * u);
  float r = __builtin_amdgcn_rcpf(z + 1.0f);
  return __builtin_fmaf(-v, r, v);
}

__device__ __forceinline__ void async16(const void* g, void* l) {
  __builtin_amdgcn_global_load_lds((const __attribute__((address_space(1))) unsigned int*)g,
                                   (__attribute__((address_space(3))) unsigned int*)l, 16, 0, 0);
}

__device__ __forceinline__ unsigned lds_off(const void* p) {
  return (unsigned)(unsigned long long)(const __attribute__((address_space(3))) void*)p;
}

// ---- merged weight prep: ALL transposes (64x64 LDS tiles) + bias concat in ONE launch.
// tiles: [0,432) wq/wk/wv -> wtqkv ; [432,576) wo ; [576,1152) w1 ; [1152,1728) w2 ;
// blocks [1728,1737) bias concat.
__global__ __launch_bounds__(256) void prep_kernel(const float* __restrict__ wq, const float* __restrict__ wk,
                                                   const float* __restrict__ wv, const float* __restrict__ wo,
                                                   const float* __restrict__ w1, const float* __restrict__ w2,
                                                   const float* __restrict__ bq, const float* __restrict__ bk,
                                                   const float* __restrict__ bv,
                                                   __bf16* __restrict__ wtqkv, __bf16* __restrict__ wto,
                                                   __bf16* __restrict__ wt1, __bf16* __restrict__ wt2,
                                                   float* __restrict__ bqkv) {
  const int id = blockIdx.x;
  if (id >= 1728) {  // bias blocks
    int i = (id - 1728) * 256 + threadIdx.x;
    if (i < 2304) bqkv[i] = (i < 768) ? bq[i] : (i < 1536) ? bk[i - 768] : bv[i - 1536];
    return;
  }
  const float* W;
  __bf16* Wt;
  int K, N, tn, tk;
  if (id < 432) {
    int w3 = id / 144, r = id % 144;
    W = (w3 == 0) ? wq : (w3 == 1) ? wk : wv;
    Wt = wtqkv + (long)w3 * 768 * 768;
    K = 768; N = 768; tn = r % 12; tk = r / 12;
  } else if (id < 576) {
    int r = id - 432;
    W = wo; Wt = wto; K = 768; N = 768; tn = r % 12; tk = r / 12;
  } else if (id < 1152) {
    int r = id - 576;
    W = w1; Wt = wt1; K = 768; N = 3072; tn = r % 48; tk = r / 48;
  } else {
    int r = id - 1152;
    W = w2; Wt = wt2; K = 3072; N = 768; tn = r % 12; tk = r / 12;
  }
  __shared__ __bf16 tile[64][65];
  const int tn0 = tn * 64, tk0 = tk * 64;
  const int tr = threadIdx.x >> 4, tc = (threadIdx.x & 15) * 4;
#pragma unroll
  for (int p = 0; p < 4; ++p) {
    int r = p * 16 + tr;
    float4 v = *(const float4*)&W[(long)(tk0 + r) * N + tn0 + tc];
    tile[tc + 0][r] = (__bf16)v.x;
    tile[tc + 1][r] = (__bf16)v.y;
    tile[tc + 2][r] = (__bf16)v.z;
    tile[tc + 3][r] = (__bf16)v.w;
  }
  __syncthreads();
#pragma unroll
  for (int p = 0; p < 4; ++p) {
    int n = p * 16 + tr;
    bf16x4 o;
    o[0] = tile[n][tc]; o[1] = tile[n][tc + 1]; o[2] = tile[n][tc + 2]; o[3] = tile[n][tc + 3];
    *(bf16x4*)&Wt[(long)(tn0 + n) * K + tk0 + tc] = o;
  }
}

// ---- layernorm: fp32 in (rows x 768), bf16 out. One block (256 thr) per row.
__global__ __launch_bounds__(256) void ln_kernel(const float* __restrict__ x, const float* __restrict__ g,
                                                 const float* __restrict__ b, __bf16* __restrict__ out) {
  int row = blockIdx.x;
  const float* xr = x + (long)row * 768;
  float v0 = xr[threadIdx.x], v1 = xr[threadIdx.x + 256], v2 = xr[threadIdx.x + 512];
  float s = v0 + v1 + v2, s2 = v0 * v0 + v1 * v1 + v2 * v2;
#pragma unroll
  for (int m = 1; m < 64; m <<= 1) { s += __shfl_xor(s, m); s2 += __shfl_xor(s2, m); }
  __shared__ float ws1[4], ws2[4];
  int wv = threadIdx.x >> 6;
  if ((threadIdx.x & 63) == 0) { ws1[wv] = s; ws2[wv] = s2; }
  __syncthreads();
  s = ws1[0] + ws1[1] + ws1[2] + ws1[3];
  s2 = ws2[0] + ws2[1] + ws2[2] + ws2[3];
  float mu = s * (1.0f / 768.0f);
  float var = s2 * (1.0f / 768.0f) - mu * mu;
  float rstd = rsqrtf(var + 1e-5f);
  __bf16* orow = out + (long)row * 768;
  orow[threadIdx.x]       = (__bf16)((v0 - mu) * rstd * g[threadIdx.x]       + b[threadIdx.x]);
  orow[threadIdx.x + 256] = (__bf16)((v1 - mu) * rstd * g[threadIdx.x + 256] + b[threadIdx.x + 256]);
  orow[threadIdx.x + 512] = (__bf16)((v2 - mu) * rstd * g[threadIdx.x + 512] + b[threadIdx.x + 512]);
}

// ---- layernorm, bf16 input variant (for x2).
__global__ __launch_bounds__(256) void ln_b_kernel(const __bf16* __restrict__ x, const float* __restrict__ g,
                                                   const float* __restrict__ b, __bf16* __restrict__ out) {
  int row = blockIdx.x;
  const __bf16* xr = x + (long)row * 768;
  float v0 = (float)xr[threadIdx.x], v1 = (float)xr[threadIdx.x + 256], v2 = (float)xr[threadIdx.x + 512];
  float s = v0 + v1 + v2, s2 = v0 * v0 + v1 * v1 + v2 * v2;
#pragma unroll
  for (int m = 1; m < 64; m <<= 1) { s += __shfl_xor(s, m); s2 += __shfl_xor(s2, m); }
  __shared__ float ws1[4], ws2[4];
  int wv = threadIdx.x >> 6;
  if ((threadIdx.x & 63) == 0) { ws1[wv] = s; ws2[wv] = s2; }
  __syncthreads();
  s = ws1[0] + ws1[1] + ws1[2] + ws1[3];
  s2 = ws2[0] + ws2[1] + ws2[2] + ws2[3];
  float mu = s * (1.0f / 768.0f);
  float var = s2 * (1.0f / 768.0f) - mu * mu;
  float rstd = rsqrtf(var + 1e-5f);
  __bf16* orow = out + (long)row * 768;
  orow[threadIdx.x]       = (__bf16)((v0 - mu) * rstd * g[threadIdx.x]       + b[threadIdx.x]);
  orow[threadIdx.x + 256] = (__bf16)((v1 - mu) * rstd * g[threadIdx.x + 256] + b[threadIdx.x + 256]);
  orow[threadIdx.x + 512] = (__bf16)((v2 - mu) * rstd * g[threadIdx.x + 512] + b[threadIdx.x + 512]);
}

// ---- GEMM: m103 structure (R12/R14/R16-verified). 128x128, BK=64, 4 waves, 32KB LDS, (256,3).
// VGPR=80, zero spill. Larger tiles (128x192) spill at this occupancy (R15) — do not enlarge.
// EPI: 0 = bf16 out; 1 = gelu -> bf16 out; 3 = +fp32 res -> bf16 out; 4 = +bf16 res -> fp32 out.
template <int EPI>
__global__ __launch_bounds__(256, 3) void gemm_kernel(const __bf16* __restrict__ A, const __bf16* __restrict__ Wt,
                                                      const float* __restrict__ bias, const float* __restrict__ resf,
                                                      const __bf16* __restrict__ resb,
                                                      float* __restrict__ outf, __bf16* __restrict__ outb,
                                                      int M, int N, int K) {
  __shared__ __align__(16) __bf16 As[8192];
  __shared__ __align__(16) __bf16 Bs[8192];
  const int tid = threadIdx.x, lane = tid & 63, w = tid >> 6;
  const int wm = w >> 1, wn = w & 1, lr = lane & 15, lh = lane >> 4;
  const int gx = gridDim.x, gy = gridDim.y;
  int id = blockIdx.x + gx * blockIdx.y;
  int xcd = id & 7, slot = id >> 3;
  int by = xcd * (gy >> 3) + slot / gx;
  int bx = slot % gx;
  const int m0 = by * 128, n0 = bx * 128;
  const int nt = K >> 6;
  int srow[4], scol[4];
#pragma unroll
  for (int l = 0; l < 4; ++l) {
    int c = l * 256 + tid;
    srow[l] = c >> 3;
    scol[l] = ((c & 7) ^ ((c >> 3) & 7)) * 8;
  }
  const __bf16* Ag = A + (long)m0 * K;
  const __bf16* Bg = Wt + (long)n0 * K;

  f32x4 acc[4][4] = {};
  for (int t = 0; t < nt; ++t) {
    const int kb = t << 6;
    __syncthreads();
#pragma unroll
    for (int l = 0; l < 4; ++l) {
      async16(Ag + (long)srow[l] * K + kb + scol[l], &As[l * 2048 + w * 512]);
      async16(Bg + (long)srow[l] * K + kb + scol[l], &Bs[l * 2048 + w * 512]);
    }
    __syncthreads();
    bf16x8 af[4][2], bfr[4][2];
#pragma unroll
    for (int m4 = 0; m4 < 4; ++m4) {
      int row = wm * 64 + m4 * 16 + lr;
#pragma unroll
      for (int kk = 0; kk < 2; ++kk)
        af[m4][kk] = *(const bf16x8*)&As[row * 64 + ((kk * 32 + lh * 8) ^ ((row & 7) << 3))];
    }
#pragma unroll
    for (int n = 0; n < 4; ++n) {
      int row = wn * 64 + n * 16 + lr;
#pragma unroll
      for (int kk = 0; kk < 2; ++kk)
        bfr[n][kk] = *(const bf16x8*)&Bs[row * 64 + ((kk * 32 + lh * 8) ^ ((row & 7) << 3))];
    }
    __builtin_amdgcn_s_setprio(1);
#pragma unroll
    for (int m4 = 0; m4 < 4; ++m4)
#pragma unroll
      for (int n = 0; n < 4; ++n) {
        acc[m4][n] = mfma16(af[m4][0], bfr[n][0], acc[m4][n]);
        acc[m4][n] = mfma16(af[m4][1], bfr[n][1], acc[m4][n]);
      }
    __builtin_amdgcn_s_setprio(0);
  }

#pragma unroll
  for (int m = 0; m < 4; ++m)
#pragma unroll
    for (int n = 0; n < 4; ++n) {
      int col = n0 + wn * 64 + n * 16 + lr;
      float bc = bias[col];
#pragma unroll
      for (int j = 0; j < 4; ++j) {
        int row = m0 + wm * 64 + m * 16 + lh * 4 + j;
        float v = acc[m][n][j] + bc;
        if (EPI == 1) v = gelu_f(v);
        if (EPI == 3) outb[(long)row * N + col] = (__bf16)(v + resf[(long)row * N + col]);
        else if (EPI == 4) outf[(long)row * N + col] = v + (float)resb[(long)row * N + col];
        else outb[(long)row * N + col] = (__bf16)v;
      }
    }
}

// ---- flash attention on fused qkv buffer (rows x 2304). (R19-verified: 8 waves / 256 q-rows,
// K/V staged once per block, 2-barrier scheme, counted lgkmcnt(15), no-max exp2 softmax.)
__global__ __launch_bounds__(512) void attn_kernel(const __bf16* __restrict__ qkv, __bf16* __restrict__ o) {
  __shared__ __bf16 K_lds[64][72];
  __shared__ __align__(16) unsigned char Vt[8448];
  __shared__ __align__(16) unsigned char Pt[8][4224];
  const int tid = threadIdx.x;
  const int lane = tid & 63, wv = tid >> 6;
  const int lr = lane & 15, lh = lane >> 4;
  const int hb = blockIdx.x, qt = blockIdx.y;
  const int h = hb % 12, bz = hb / 12;
  const int qrow0 = bz * 1024 + qt * 256 + wv * 32;
  const int hcol = h * 64;
  const __bf16* q = qkv + hcol;
  const __bf16* k = qkv + 768 + hcol;
  const __bf16* v = qkv + 1536 + hcol;
  const float QSC = 0.18033688011112042f;  // 0.125 * log2(e)
  bf16x8 aq[2][2];
#pragma unroll
  for (int r = 0; r < 2; ++r)
#pragma unroll
    for (int kk = 0; kk < 2; ++kk) {
      bf16x8 t = *(const bf16x8*)(q + (long)(qrow0 + r * 16 + lr) * 2304 + kk * 32 + lh * 8);
#pragma unroll
      for (int e = 0; e < 8; ++e) t[e] = (__bf16)((float)t[e] * QSC);
      aq[r][kk] = t;
    }
  bf16x8 ones;
#pragma unroll
  for (int e = 0; e < 8; ++e) ones[e] = (__bf16)1.0f;
  f32x4 o_fr[2][4] = {};
  float l_s[2][4];
#pragma unroll
  for (int r = 0; r < 2; ++r)
#pragma unroll
    for (int j = 0; j < 4; ++j) l_s[r][j] = 0.0f;
  const int r0 = tid >> 3, c0 = (tid & 7) * 8;   // r0 in [0,64) with 512 threads
  const unsigned vt0 = lds_off(Vt) + (lane >> 4) * 1056 + (lane & 15) * 2;
  const int Tst = (r0 >> 2) * 4 + (c0 >> 4);
  const int vb = Tst * 128 + (r0 & 3) * 32 + (c0 & 15) * 2 + (Tst >> 3) * 32;
  const unsigned pwb = lds_off(&Pt[wv][0]) + (lr >> 2) * 256 + (lr & 3) * 32 + lh * 8;
  const unsigned prb = lds_off(&Pt[wv][0]) + lh * 512 + (lh >> 1) * 32 + lr * 2;

  const __bf16* kp = k + (long)(bz * 1024 + r0) * 2304 + c0;
  const __bf16* vp = v + (long)(bz * 1024 + r0) * 2304 + c0;
  bf16x8 rK = *(const bf16x8*)kp;
  bf16x8 rV = *(const bf16x8*)vp;
  *(bf16x8*)&K_lds[r0][c0] = rK;
  *(bf16x8*)(Vt + vb) = rV;
  __syncthreads();

  for (int t = 0; t < 16; ++t) {
    bf16x8 bk[4][2];
#pragma unroll
    for (int n = 0; n < 4; ++n)
#pragma unroll
      for (int kk = 0; kk < 2; ++kk)
        bk[n][kk] = *(const bf16x8*)&K_lds[n * 16 + lr][kk * 32 + lh * 8];
    if (t < 15) {
      kp += 64 * 2304; vp += 64 * 2304;
      rK = *(const bf16x8*)kp;
      rV = *(const bf16x8*)vp;
    }
    f32x4 sf[2][4];
    __builtin_amdgcn_s_setprio(1);
#pragma unroll
    for (int r = 0; r < 2; ++r)
#pragma unroll
      for (int n = 0; n < 4; ++n) {
        f32x4 s = {0.f, 0.f, 0.f, 0.f};
        s = mfma16(aq[r][0], bk[n][0], s);
        s = mfma16(aq[r][1], bk[n][1], s);
        sf[r][n] = s;
      }
    __builtin_amdgcn_s_setprio(0);
#define PW(rr, nn)                                                                     \
    {                                                                                  \
      float e0 = __builtin_amdgcn_exp2f(sf[rr][nn][0]);                                \
      float e1 = __builtin_amdgcn_exp2f(sf[rr][nn][1]);                                \
      float e2 = __builtin_amdgcn_exp2f(sf[rr][nn][2]);                                \
      float e3 = __builtin_amdgcn_exp2f(sf[rr][nn][3]);                                \
      u32x2 d;                                                                         \
      asm("v_cvt_pk_bf16_f32 %0, %1, %2" : "=v"(d[0]) : "v"(e0), "v"(e1));             \
      asm("v_cvt_pk_bf16_f32 %0, %1, %2" : "=v"(d[1]) : "v"(e2), "v"(e3));             \
      asm volatile("ds_write_b64 %0, %1 offset:%2" ::"v"(pwb), "v"(d),                 \
                   "i"((nn)*1056 + (rr)*128) : "memory");                              \
    }
    PW(0, 0) PW(0, 1) PW(0, 2) PW(0, 3) PW(1, 0) PW(1, 1) PW(1, 2) PW(1, 3)
#undef PW
    u32x2 trv[4][2][2];
#pragma unroll
    for (int d0 = 0; d0 < 4; ++d0)
#pragma unroll
      for (int ks = 0; ks < 2; ++ks) {
        unsigned a = vt0 + ks * 4224 + d0 * 128;
        asm volatile("ds_read_b64_tr_b16 %0, %1" : "=v"(trv[d0][ks][0]) : "v"(a));
        asm volatile("ds_read_b64_tr_b16 %0, %1 offset:512" : "=v"(trv[d0][ks][1]) : "v"(a));
      }
    asm volatile("s_waitcnt lgkmcnt(15)" ::: "memory");
    __builtin_amdgcn_sched_barrier(0);
    u32x2 trp[2][2][2];
#define PR(rr, kks)                                                                     \
    asm volatile("ds_read_b64_tr_b16 %0, %1 offset:%2"                                  \
                 : "=v"(trp[rr][kks][0]) : "v"(prb), "i"((rr)*128 + (kks)*2112));       \
    asm volatile("ds_read_b64_tr_b16 %0, %1 offset:%2"                                  \
                 : "=v"(trp[rr][kks][1]) : "v"(prb), "i"((rr)*128 + (kks)*2112 + 256));
    PR(0, 0) PR(0, 1) PR(1, 0) PR(1, 1)
#undef PR
    asm volatile("s_waitcnt lgkmcnt(0)" ::: "memory");
    __builtin_amdgcn_sched_barrier(0);
    __syncthreads();
    if (t < 15) {
      *(bf16x8*)&K_lds[r0][c0] = rK;
      *(bf16x8*)(Vt + vb) = rV;
    }
    bf16x8 ap[2][2];
#pragma unroll
    for (int r = 0; r < 2; ++r)
#pragma unroll
      for (int ks = 0; ks < 2; ++ks) {
        union { u32x2 u[2]; bf16x8 v8; } pu;
        pu.u[0] = trp[r][ks][0];
        pu.u[1] = trp[r][ks][1];
        ap[r][ks] = pu.v8;
      }
    __builtin_amdgcn_s_setprio(1);
#pragma unroll
    for (int r = 0; r < 2; ++r) {
      f32x4 ls = {0.f, 0.f, 0.f, 0.f};
      ls = mfma16(ap[r][0], ones, ls);
      ls = mfma16(ap[r][1], ones, ls);
#pragma unroll
      for (int j = 0; j < 4; ++j) l_s[r][j] += ls[j];
    }
#pragma unroll
    for (int d0 = 0; d0 < 4; ++d0) {
      union { u32x2 u[2]; bf16x8 v8; } b0, b1;
      b0.u[0] = trv[d0][0][0]; b0.u[1] = trv[d0][0][1];
      b1.u[0] = trv[d0][1][0]; b1.u[1] = trv[d0][1][1];
#pragma unroll
      for (int r = 0; r < 2; ++r) {
        o_fr[r][d0] = mfma16(ap[r][0], b0.v8, o_fr[r][d0]);
        o_fr[r][d0] = mfma16(ap[r][1], b1.v8, o_fr[r][d0]);
      }
    }
    __builtin_amdgcn_s_setprio(0);
    if (t < 15) __syncthreads();
  }
#pragma unroll
  for (int r = 0; r < 2; ++r)
#pragma unroll
    for (int d = 0; d < 4; ++d)
#pragma unroll
      for (int j = 0; j < 4; ++j) {
        int row = qrow0 + r * 16 + lh * 4 + j;
        int col = hcol + d * 16 + lr;
        o[(long)row * 768 + col] = (__bf16)(o_fr[r][d][j] * (1.0f / l_s[r][j]));
      }
}

extern "C" void kernel_launch(void* const* d_in, const int* in_sizes, int n_in,
                              void* d_out, int out_size, void* d_ws, size_t ws_size,
                              hipStream_t stream) {
  const float* x    = (const float*)d_in[0];
  const float* ln1g = (const float*)d_in[1];
  const float* ln1b = (const float*)d_in[2];
  const float* wq   = (const float*)d_in[3];
  const float* bq   = (const float*)d_in[4];
  const float* wk   = (const float*)d_in[5];
  const float* bk   = (const float*)d_in[6];
  const float* wv   = (const float*)d_in[7];
  const float* bv   = (const float*)d_in[8];
  const float* wo   = (const float*)d_in[9];
  const float* bo   = (const float*)d_in[10];
  const float* ln2g = (const float*)d_in[11];
  const float* ln2b = (const float*)d_in[12];
  const float* w1   = (const float*)d_in[13];
  const float* b1   = (const float*)d_in[14];
  const float* w2   = (const float*)d_in[15];
  const float* b2   = (const float*)d_in[16];
  float* out = (float*)d_out;
  char* ws = (char*)d_ws;

  const long SD = 16384L * 768;
  const long SF = 16384L * 3072;

  __bf16* qkv = (__bf16*)(ws);                      // 16384 x 2304
  __bf16* f1  = (__bf16*)(ws);                      // aliases qkv (dead by FFN1)
  __bf16* hb  = (__bf16*)(ws + 2 * SF);             // LN1 out; later attn out
  __bf16* x2  = (__bf16*)(ws + 2 * SF + 2 * SD);    // bf16
  __bf16* h2  = (__bf16*)(ws + 2 * SF + 2 * SD + 4 * SD);
  __bf16* wtqkv = (__bf16*)(ws + 2 * SF + 2 * SD + 4 * SD + 2 * SD);  // 2304 x 768
  __bf16* wto = wtqkv + 2304L * 768;
  __bf16* wt1 = wto + 768L * 768;
  __bf16* wt2 = wt1 + 768L * 3072;
  float*  bqkv = (float*)(wt2 + 3072L * 768);

  // merged prep: all weight transposes + bias concat in one launch
  prep_kernel<<<1737, 256, 0, stream>>>(wq, wk, wv, wo, w1, w2, bq, bk, bv,
                                        wtqkv, wto, wt1, wt2, bqkv);

  ln_kernel<<<16384, 256, 0, stream>>>(x, ln1g, ln1b, hb);
  gemm_kernel<0><<<dim3(18, 128), 256, 0, stream>>>(hb, wtqkv, bqkv, nullptr, nullptr, nullptr, qkv, 16384, 2304, 768);
  attn_kernel<<<dim3(192, 4), 512, 0, stream>>>(qkv, hb);
  gemm_kernel<3><<<dim3(6, 128), 256, 0, stream>>>(hb, wto, bo, x, nullptr, nullptr, x2, 16384, 768, 768);
  ln_b_kernel<<<16384, 256, 0, stream>>>(x2, ln2g, ln2b, h2);
  gemm_kernel<1><<<dim3(24, 128), 256, 0, stream>>>(h2, wt1, b1, nullptr, nullptr, nullptr, f1, 16384, 3072, 768);
  gemm_kernel<4><<<dim3(6, 128), 256, 0, stream>>>(f1, wt2, b2, nullptr, x2, out, nullptr, 16384, 768, 3072);
}

// Round 21
// 352.576 us; speedup vs baseline: 1.0824x; 1.0089x over previous
//
#include <hip/hip_runtime.h>
#include <hip/hip_bf16.h>
#include <math.h>

typedef __bf16 bf16x8 __attribute__((ext_vector_type(8)));
typedef __bf16 bf16x4 __attribute__((ext_vector_type(4)));
typedef float f32x4 __attribute__((ext_vector_type(4)));
typedef unsigned int u32x2 __attribute__((ext_vector_type(2)));

__device__ __forceinline__ f32x4 mfma16(bf16x8 a, bf16x8 b, f32x4 c) {
  return __builtin_amdgcn_mfma_f32_16x16x32_bf16(a, b, c, 0, 0, 0);
}

// fast tanh-form GELU via native exp2 (R13, verified)
__device__ __forceinline__ float gelu_f(float v) {
  float x2 = v * v;
  float u = v * __builtin_fmaf(0.044715f, x2, 1.0f);
  float z = __builtin_amdgcn_exp2f(2.302101862f * u);
  float r = __builtin_amdgcn_rcpf(z + 1.0f);
  return __builtin_fmaf(-v, r, v);
}

__device__ __forceinline__ void async16(const void* g, void* l) {
  __builtin_amdgcn_global_load_lds((const __attribute__((address_space(1))) unsigned int*)g,
                                   (__attribute__((address_space(3))) unsigned int*)l, 16, 0, 0);
}

__device__ __forceinline__ unsigned lds_off(const void* p) {
  return (unsigned)(unsigned long long)(const __attribute__((address_space(3))) void*)p;
}

// ---- merged weight prep: ALL transposes (64x64 LDS tiles) + bias concat in ONE launch.
__global__ __launch_bounds__(256) void prep_kernel(const float* __restrict__ wq, const float* __restrict__ wk,
                                                   const float* __restrict__ wv, const float* __restrict__ wo,
                                                   const float* __restrict__ w1, const float* __restrict__ w2,
                                                   const float* __restrict__ bq, const float* __restrict__ bk,
                                                   const float* __restrict__ bv,
                                                   __bf16* __restrict__ wtqkv, __bf16* __restrict__ wto,
                                                   __bf16* __restrict__ wt1, __bf16* __restrict__ wt2,
                                                   float* __restrict__ bqkv) {
  const int id = blockIdx.x;
  if (id >= 1728) {  // bias blocks
    int i = (id - 1728) * 256 + threadIdx.x;
    if (i < 2304) bqkv[i] = (i < 768) ? bq[i] : (i < 1536) ? bk[i - 768] : bv[i - 1536];
    return;
  }
  const float* W;
  __bf16* Wt;
  int K, N, tn, tk;
  if (id < 432) {
    int w3 = id / 144, r = id % 144;
    W = (w3 == 0) ? wq : (w3 == 1) ? wk : wv;
    Wt = wtqkv + (long)w3 * 768 * 768;
    K = 768; N = 768; tn = r % 12; tk = r / 12;
  } else if (id < 576) {
    int r = id - 432;
    W = wo; Wt = wto; K = 768; N = 768; tn = r % 12; tk = r / 12;
  } else if (id < 1152) {
    int r = id - 576;
    W = w1; Wt = wt1; K = 768; N = 3072; tn = r % 48; tk = r / 48;
  } else {
    int r = id - 1152;
    W = w2; Wt = wt2; K = 3072; N = 768; tn = r % 12; tk = r / 12;
  }
  __shared__ __bf16 tile[64][65];
  const int tn0 = tn * 64, tk0 = tk * 64;
  const int tr = threadIdx.x >> 4, tc = (threadIdx.x & 15) * 4;
#pragma unroll
  for (int p = 0; p < 4; ++p) {
    int r = p * 16 + tr;
    float4 v = *(const float4*)&W[(long)(tk0 + r) * N + tn0 + tc];
    tile[tc + 0][r] = (__bf16)v.x;
    tile[tc + 1][r] = (__bf16)v.y;
    tile[tc + 2][r] = (__bf16)v.z;
    tile[tc + 3][r] = (__bf16)v.w;
  }
  __syncthreads();
#pragma unroll
  for (int p = 0; p < 4; ++p) {
    int n = p * 16 + tr;
    bf16x4 o;
    o[0] = tile[n][tc]; o[1] = tile[n][tc + 1]; o[2] = tile[n][tc + 2]; o[3] = tile[n][tc + 3];
    *(bf16x4*)&Wt[(long)(tn0 + n) * K + tk0 + tc] = o;
  }
}

// ---- layernorm: fp32 in (rows x 768), bf16 out. One block (256 thr) per row.
__global__ __launch_bounds__(256) void ln_kernel(const float* __restrict__ x, const float* __restrict__ g,
                                                 const float* __restrict__ b, __bf16* __restrict__ out) {
  int row = blockIdx.x;
  const float* xr = x + (long)row * 768;
  float v0 = xr[threadIdx.x], v1 = xr[threadIdx.x + 256], v2 = xr[threadIdx.x + 512];
  float s = v0 + v1 + v2, s2 = v0 * v0 + v1 * v1 + v2 * v2;
#pragma unroll
  for (int m = 1; m < 64; m <<= 1) { s += __shfl_xor(s, m); s2 += __shfl_xor(s2, m); }
  __shared__ float ws1[4], ws2[4];
  int wv = threadIdx.x >> 6;
  if ((threadIdx.x & 63) == 0) { ws1[wv] = s; ws2[wv] = s2; }
  __syncthreads();
  s = ws1[0] + ws1[1] + ws1[2] + ws1[3];
  s2 = ws2[0] + ws2[1] + ws2[2] + ws2[3];
  float mu = s * (1.0f / 768.0f);
  float var = s2 * (1.0f / 768.0f) - mu * mu;
  float rstd = rsqrtf(var + 1e-5f);
  __bf16* orow = out + (long)row * 768;
  orow[threadIdx.x]       = (__bf16)((v0 - mu) * rstd * g[threadIdx.x]       + b[threadIdx.x]);
  orow[threadIdx.x + 256] = (__bf16)((v1 - mu) * rstd * g[threadIdx.x + 256] + b[threadIdx.x + 256]);
  orow[threadIdx.x + 512] = (__bf16)((v2 - mu) * rstd * g[threadIdx.x + 512] + b[threadIdx.x + 512]);
}

// ---- layernorm, bf16 input variant (for x2).
__global__ __launch_bounds__(256) void ln_b_kernel(const __bf16* __restrict__ x, const float* __restrict__ g,
                                                   const float* __restrict__ b, __bf16* __restrict__ out) {
  int row = blockIdx.x;
  const __bf16* xr = x + (long)row * 768;
  float v0 = (float)xr[threadIdx.x], v1 = (float)xr[threadIdx.x + 256], v2 = (float)xr[threadIdx.x + 512];
  float s = v0 + v1 + v2, s2 = v0 * v0 + v1 * v1 + v2 * v2;
#pragma unroll
  for (int m = 1; m < 64; m <<= 1) { s += __shfl_xor(s, m); s2 += __shfl_xor(s2, m); }
  __shared__ float ws1[4], ws2[4];
  int wv = threadIdx.x >> 6;
  if ((threadIdx.x & 63) == 0) { ws1[wv] = s; ws2[wv] = s2; }
  __syncthreads();
  s = ws1[0] + ws1[1] + ws1[2] + ws1[3];
  s2 = ws2[0] + ws2[1] + ws2[2] + ws2[3];
  float mu = s * (1.0f / 768.0f);
  float var = s2 * (1.0f / 768.0f) - mu * mu;
  float rstd = rsqrtf(var + 1e-5f);
  __bf16* orow = out + (long)row * 768;
  orow[threadIdx.x]       = (__bf16)((v0 - mu) * rstd * g[threadIdx.x]       + b[threadIdx.x]);
  orow[threadIdx.x + 256] = (__bf16)((v1 - mu) * rstd * g[threadIdx.x + 256] + b[threadIdx.x + 256]);
  orow[threadIdx.x + 512] = (__bf16)((v2 - mu) * rstd * g[threadIdx.x + 512] + b[threadIdx.x + 512]);
}

// ---- GEMM: m103 structure (R12/R14/R16-verified). 128x128, BK=64, 4 waves, 32KB LDS, (256,3).
// R21: bx-major-within-XCD ordering — per XCD the 16 A-panels (3.1MB) + current B-panel (196KB)
// are L2-resident, so staging loads hit L2 (~200cyc) instead of HBM (~900cyc), shortening the
// per-tile vmcnt drain. VGPR=80 zero-spill; do not enlarge tile (R15) or raise occupancy (R10).
template <int EPI>
__global__ __launch_bounds__(256, 3) void gemm_kernel(const __bf16* __restrict__ A, const __bf16* __restrict__ Wt,
                                                      const float* __restrict__ bias, const float* __restrict__ resf,
                                                      const __bf16* __restrict__ resb,
                                                      float* __restrict__ outf, __bf16* __restrict__ outb,
                                                      int M, int N, int K) {
  __shared__ __align__(16) __bf16 As[8192];
  __shared__ __align__(16) __bf16 Bs[8192];
  const int tid = threadIdx.x, lane = tid & 63, w = tid >> 6;
  const int wm = w >> 1, wn = w & 1, lr = lane & 15, lh = lane >> 4;
  const int gx = gridDim.x, gy = gridDim.y;
  int id = blockIdx.x + gx * blockIdx.y;
  int xcd = id & 7, slot = id >> 3;
  const int gy8 = gy >> 3;
  int bx = slot / gy8;                  // bx-major within XCD
  int by = xcd * gy8 + slot % gy8;
  const int m0 = by * 128, n0 = bx * 128;
  const int nt = K >> 6;
  int srow[4], scol[4];
#pragma unroll
  for (int l = 0; l < 4; ++l) {
    int c = l * 256 + tid;
    srow[l] = c >> 3;
    scol[l] = ((c & 7) ^ ((c >> 3) & 7)) * 8;
  }
  const __bf16* Ag = A + (long)m0 * K;
  const __bf16* Bg = Wt + (long)n0 * K;

  f32x4 acc[4][4] = {};
  for (int t = 0; t < nt; ++t) {
    const int kb = t << 6;
    __syncthreads();
#pragma unroll
    for (int l = 0; l < 4; ++l) {
      async16(Ag + (long)srow[l] * K + kb + scol[l], &As[l * 2048 + w * 512]);
      async16(Bg + (long)srow[l] * K + kb + scol[l], &Bs[l * 2048 + w * 512]);
    }
    __syncthreads();
    bf16x8 af[4][2], bfr[4][2];
#pragma unroll
    for (int m4 = 0; m4 < 4; ++m4) {
      int row = wm * 64 + m4 * 16 + lr;
#pragma unroll
      for (int kk = 0; kk < 2; ++kk)
        af[m4][kk] = *(const bf16x8*)&As[row * 64 + ((kk * 32 + lh * 8) ^ ((row & 7) << 3))];
    }
#pragma unroll
    for (int n = 0; n < 4; ++n) {
      int row = wn * 64 + n * 16 + lr;
#pragma unroll
      for (int kk = 0; kk < 2; ++kk)
        bfr[n][kk] = *(const bf16x8*)&Bs[row * 64 + ((kk * 32 + lh * 8) ^ ((row & 7) << 3))];
    }
    __builtin_amdgcn_s_setprio(1);
#pragma unroll
    for (int m4 = 0; m4 < 4; ++m4)
#pragma unroll
      for (int n = 0; n < 4; ++n) {
        acc[m4][n] = mfma16(af[m4][0], bfr[n][0], acc[m4][n]);
        acc[m4][n] = mfma16(af[m4][1], bfr[n][1], acc[m4][n]);
      }
    __builtin_amdgcn_s_setprio(0);
  }

#pragma unroll
  for (int m = 0; m < 4; ++m)
#pragma unroll
    for (int n = 0; n < 4; ++n) {
      int col = n0 + wn * 64 + n * 16 + lr;
      float bc = bias[col];
#pragma unroll
      for (int j = 0; j < 4; ++j) {
        int row = m0 + wm * 64 + m * 16 + lh * 4 + j;
        float v = acc[m][n][j] + bc;
        if (EPI == 1) v = gelu_f(v);
        if (EPI == 3) outb[(long)row * N + col] = (__bf16)(v + resf[(long)row * N + col]);
        else if (EPI == 4) outf[(long)row * N + col] = v + (float)resb[(long)row * N + col];
        else outb[(long)row * N + col] = (__bf16)v;
      }
    }
}

// ---- flash attention on fused qkv buffer (rows x 2304). (R19-verified: 8 waves / 256 q-rows,
// K/V staged once per block, 2-barrier scheme, counted lgkmcnt(15), no-max exp2 softmax.)
__global__ __launch_bounds__(512) void attn_kernel(const __bf16* __restrict__ qkv, __bf16* __restrict__ o) {
  __shared__ __bf16 K_lds[64][72];
  __shared__ __align__(16) unsigned char Vt[8448];
  __shared__ __align__(16) unsigned char Pt[8][4224];
  const int tid = threadIdx.x;
  const int lane = tid & 63, wv = tid >> 6;
  const int lr = lane & 15, lh = lane >> 4;
  const int hb = blockIdx.x, qt = blockIdx.y;
  const int h = hb % 12, bz = hb / 12;
  const int qrow0 = bz * 1024 + qt * 256 + wv * 32;
  const int hcol = h * 64;
  const __bf16* q = qkv + hcol;
  const __bf16* k = qkv + 768 + hcol;
  const __bf16* v = qkv + 1536 + hcol;
  const float QSC = 0.18033688011112042f;  // 0.125 * log2(e)
  bf16x8 aq[2][2];
#pragma unroll
  for (int r = 0; r < 2; ++r)
#pragma unroll
    for (int kk = 0; kk < 2; ++kk) {
      bf16x8 t = *(const bf16x8*)(q + (long)(qrow0 + r * 16 + lr) * 2304 + kk * 32 + lh * 8);
#pragma unroll
      for (int e = 0; e < 8; ++e) t[e] = (__bf16)((float)t[e] * QSC);
      aq[r][kk] = t;
    }
  bf16x8 ones;
#pragma unroll
  for (int e = 0; e < 8; ++e) ones[e] = (__bf16)1.0f;
  f32x4 o_fr[2][4] = {};
  float l_s[2][4];
#pragma unroll
  for (int r = 0; r < 2; ++r)
#pragma unroll
    for (int j = 0; j < 4; ++j) l_s[r][j] = 0.0f;
  const int r0 = tid >> 3, c0 = (tid & 7) * 8;   // r0 in [0,64) with 512 threads
  const unsigned vt0 = lds_off(Vt) + (lane >> 4) * 1056 + (lane & 15) * 2;
  const int Tst = (r0 >> 2) * 4 + (c0 >> 4);
  const int vb = Tst * 128 + (r0 & 3) * 32 + (c0 & 15) * 2 + (Tst >> 3) * 32;
  const unsigned pwb = lds_off(&Pt[wv][0]) + (lr >> 2) * 256 + (lr & 3) * 32 + lh * 8;
  const unsigned prb = lds_off(&Pt[wv][0]) + lh * 512 + (lh >> 1) * 32 + lr * 2;

  const __bf16* kp = k + (long)(bz * 1024 + r0) * 2304 + c0;
  const __bf16* vp = v + (long)(bz * 1024 + r0) * 2304 + c0;
  bf16x8 rK = *(const bf16x8*)kp;
  bf16x8 rV = *(const bf16x8*)vp;
  *(bf16x8*)&K_lds[r0][c0] = rK;
  *(bf16x8*)(Vt + vb) = rV;
  __syncthreads();

  for (int t = 0; t < 16; ++t) {
    bf16x8 bk[4][2];
#pragma unroll
    for (int n = 0; n < 4; ++n)
#pragma unroll
      for (int kk = 0; kk < 2; ++kk)
        bk[n][kk] = *(const bf16x8*)&K_lds[n * 16 + lr][kk * 32 + lh * 8];
    if (t < 15) {
      kp += 64 * 2304; vp += 64 * 2304;
      rK = *(const bf16x8*)kp;
      rV = *(const bf16x8*)vp;
    }
    f32x4 sf[2][4];
    __builtin_amdgcn_s_setprio(1);
#pragma unroll
    for (int r = 0; r < 2; ++r)
#pragma unroll
      for (int n = 0; n < 4; ++n) {
        f32x4 s = {0.f, 0.f, 0.f, 0.f};
        s = mfma16(aq[r][0], bk[n][0], s);
        s = mfma16(aq[r][1], bk[n][1], s);
        sf[r][n] = s;
      }
    __builtin_amdgcn_s_setprio(0);
#define PW(rr, nn)                                                                     \
    {                                                                                  \
      float e0 = __builtin_amdgcn_exp2f(sf[rr][nn][0]);                                \
      float e1 = __builtin_amdgcn_exp2f(sf[rr][nn][1]);                                \
      float e2 = __builtin_amdgcn_exp2f(sf[rr][nn][2]);                                \
      float e3 = __builtin_amdgcn_exp2f(sf[rr][nn][3]);                                \
      u32x2 d;                                                                         \
      asm("v_cvt_pk_bf16_f32 %0, %1, %2" : "=v"(d[0]) : "v"(e0), "v"(e1));             \
      asm("v_cvt_pk_bf16_f32 %0, %1, %2" : "=v"(d[1]) : "v"(e2), "v"(e3));             \
      asm volatile("ds_write_b64 %0, %1 offset:%2" ::"v"(pwb), "v"(d),                 \
                   "i"((nn)*1056 + (rr)*128) : "memory");                              \
    }
    PW(0, 0) PW(0, 1) PW(0, 2) PW(0, 3) PW(1, 0) PW(1, 1) PW(1, 2) PW(1, 3)
#undef PW
    u32x2 trv[4][2][2];
#pragma unroll
    for (int d0 = 0; d0 < 4; ++d0)
#pragma unroll
      for (int ks = 0; ks < 2; ++ks) {
        unsigned a = vt0 + ks * 4224 + d0 * 128;
        asm volatile("ds_read_b64_tr_b16 %0, %1" : "=v"(trv[d0][ks][0]) : "v"(a));
        asm volatile("ds_read_b64_tr_b16 %0, %1 offset:512" : "=v"(trv[d0][ks][1]) : "v"(a));
      }
    asm volatile("s_waitcnt lgkmcnt(15)" ::: "memory");
    __builtin_amdgcn_sched_barrier(0);
    u32x2 trp[2][2][2];
#define PR(rr, kks)                                                                     \
    asm volatile("ds_read_b64_tr_b16 %0, %1 offset:%2"                                  \
                 : "=v"(trp[rr][kks][0]) : "v"(prb), "i"((rr)*128 + (kks)*2112));       \
    asm volatile("ds_read_b64_tr_b16 %0, %1 offset:%2"                                  \
                 : "=v"(trp[rr][kks][1]) : "v"(prb), "i"((rr)*128 + (kks)*2112 + 256));
    PR(0, 0) PR(0, 1) PR(1, 0) PR(1, 1)
#undef PR
    asm volatile("s_waitcnt lgkmcnt(0)" ::: "memory");
    __builtin_amdgcn_sched_barrier(0);
    __syncthreads();
    if (t < 15) {
      *(bf16x8*)&K_lds[r0][c0] = rK;
      *(bf16x8*)(Vt + vb) = rV;
    }
    bf16x8 ap[2][2];
#pragma unroll
    for (int r = 0; r < 2; ++r)
#pragma unroll
      for (int ks = 0; ks < 2; ++ks) {
        union { u32x2 u[2]; bf16x8 v8; } pu;
        pu.u[0] = trp[r][ks][0];
        pu.u[1] = trp[r][ks][1];
        ap[r][ks] = pu.v8;
      }
    __builtin_amdgcn_s_setprio(1);
#pragma unroll
    for (int r = 0; r < 2; ++r) {
      f32x4 ls = {0.f, 0.f, 0.f, 0.f};
      ls = mfma16(ap[r][0], ones, ls);
      ls = mfma16(ap[r][1], ones, ls);
#pragma unroll
      for (int j = 0; j < 4; ++j) l_s[r][j] += ls[j];
    }
#pragma unroll
    for (int d0 = 0; d0 < 4; ++d0) {
      union { u32x2 u[2]; bf16x8 v8; } b0, b1;
      b0.u[0] = trv[d0][0][0]; b0.u[1] = trv[d0][0][1];
      b1.u[0] = trv[d0][1][0]; b1.u[1] = trv[d0][1][1];
#pragma unroll
      for (int r = 0; r < 2; ++r) {
        o_fr[r][d0] = mfma16(ap[r][0], b0.v8, o_fr[r][d0]);
        o_fr[r][d0] = mfma16(ap[r][1], b1.v8, o_fr[r][d0]);
      }
    }
    __builtin_amdgcn_s_setprio(0);
    if (t < 15) __syncthreads();
  }
#pragma unroll
  for (int r = 0; r < 2; ++r)
#pragma unroll
    for (int d = 0; d < 4; ++d)
#pragma unroll
      for (int j = 0; j < 4; ++j) {
        int row = qrow0 + r * 16 + lh * 4 + j;
        int col = hcol + d * 16 + lr;
        o[(long)row * 768 + col] = (__bf16)(o_fr[r][d][j] * (1.0f / l_s[r][j]));
      }
}

extern "C" void kernel_launch(void* const* d_in, const int* in_sizes, int n_in,
                              void* d_out, int out_size, void* d_ws, size_t ws_size,
                              hipStream_t stream) {
  const float* x    = (const float*)d_in[0];
  const float* ln1g = (const float*)d_in[1];
  const float* ln1b = (const float*)d_in[2];
  const float* wq   = (const float*)d_in[3];
  const float* bq   = (const float*)d_in[4];
  const float* wk   = (const float*)d_in[5];
  const float* bk   = (const float*)d_in[6];
  const float* wv   = (const float*)d_in[7];
  const float* bv   = (const float*)d_in[8];
  const float* wo   = (const float*)d_in[9];
  const float* bo   = (const float*)d_in[10];
  const float* ln2g = (const float*)d_in[11];
  const float* ln2b = (const float*)d_in[12];
  const float* w1   = (const float*)d_in[13];
  const float* b1   = (const float*)d_in[14];
  const float* w2   = (const float*)d_in[15];
  const float* b2   = (const float*)d_in[16];
  float* out = (float*)d_out;
  char* ws = (char*)d_ws;

  const long SD = 16384L * 768;
  const long SF = 16384L * 3072;

  __bf16* qkv = (__bf16*)(ws);                      // 16384 x 2304
  __bf16* f1  = (__bf16*)(ws);                      // aliases qkv (dead by FFN1)
  __bf16* hb  = (__bf16*)(ws + 2 * SF);             // LN1 out; later attn out
  __bf16* x2  = (__bf16*)(ws + 2 * SF + 2 * SD);    // bf16
  __bf16* h2  = (__bf16*)(ws + 2 * SF + 2 * SD + 4 * SD);
  __bf16* wtqkv = (__bf16*)(ws + 2 * SF + 2 * SD + 4 * SD + 2 * SD);  // 2304 x 768
  __bf16* wto = wtqkv + 2304L * 768;
  __bf16* wt1 = wto + 768L * 768;
  __bf16* wt2 = wt1 + 768L * 3072;
  float*  bqkv = (float*)(wt2 + 3072L * 768);

  prep_kernel<<<1737, 256, 0, stream>>>(wq, wk, wv, wo, w1, w2, bq, bk, bv,
                                        wtqkv, wto, wt1, wt2, bqkv);

  ln_kernel<<<16384, 256, 0, stream>>>(x, ln1g, ln1b, hb);
  gemm_kernel<0><<<dim3(18, 128), 256, 0, stream>>>(hb, wtqkv, bqkv, nullptr, nullptr, nullptr, qkv, 16384, 2304, 768);
  attn_kernel<<<dim3(192, 4), 512, 0, stream>>>(qkv, hb);
  gemm_kernel<3><<<dim3(6, 128), 256, 0, stream>>>(hb, wto, bo, x, nullptr, nullptr, x2, 16384, 768, 768);
  ln_b_kernel<<<16384, 256, 0, stream>>>(x2, ln2g, ln2b, h2);
  gemm_kernel<1><<<dim3(24, 128), 256, 0, stream>>>(h2, wt1, b1, nullptr, nullptr, nullptr, f1, 16384, 3072, 768);
  gemm_kernel<4><<<dim3(6, 128), 256, 0, stream>>>(f1, wt2, b2, nullptr, x2, out, nullptr, 16384, 768, 3072);
}

// Round 22
// 352.360 us; speedup vs baseline: 1.0831x; 1.0006x over previous
//
#include <hip/hip_runtime.h>
#include <hip/hip_bf16.h>
#include <math.h>

typedef __bf16 bf16x8 __attribute__((ext_vector_type(8)));
typedef __bf16 bf16x4 __attribute__((ext_vector_type(4)));
typedef float f32x4 __attribute__((ext_vector_type(4)));
typedef unsigned int u32x2 __attribute__((ext_vector_type(2)));

__device__ __forceinline__ f32x4 mfma16(bf16x8 a, bf16x8 b, f32x4 c) {
  return __builtin_amdgcn_mfma_f32_16x16x32_bf16(a, b, c, 0, 0, 0);
}

// fast tanh-form GELU via native exp2 (R13, verified)
__device__ __forceinline__ float gelu_f(float v) {
  float x2 = v * v;
  float u = v * __builtin_fmaf(0.044715f, x2, 1.0f);
  float z = __builtin_amdgcn_exp2f(2.302101862f * u);
  float r = __builtin_amdgcn_rcpf(z + 1.0f);
  return __builtin_fmaf(-v, r, v);
}

__device__ __forceinline__ void async16(const void* g, void* l) {
  __builtin_amdgcn_global_load_lds((const __attribute__((address_space(1))) unsigned int*)g,
                                   (__attribute__((address_space(3))) unsigned int*)l, 16, 0, 0);
}

__device__ __forceinline__ unsigned lds_off(const void* p) {
  return (unsigned)(unsigned long long)(const __attribute__((address_space(3))) void*)p;
}

// ---- merged prologue: LN1 (blocks [0,16384)) + ALL weight transposes + bias concat
// (blocks [16384, 16384+1737)) in ONE launch — independent work, runs concurrently.
__global__ __launch_bounds__(256) void prep_ln_kernel(
    const float* __restrict__ x, const float* __restrict__ ln1g, const float* __restrict__ ln1b,
    __bf16* __restrict__ hb,
    const float* __restrict__ wq, const float* __restrict__ wk, const float* __restrict__ wv,
    const float* __restrict__ wo, const float* __restrict__ w1, const float* __restrict__ w2,
    const float* __restrict__ bq, const float* __restrict__ bk, const float* __restrict__ bv,
    __bf16* __restrict__ wtqkv, __bf16* __restrict__ wto,
    __bf16* __restrict__ wt1, __bf16* __restrict__ wt2, float* __restrict__ bqkv) {
  __shared__ __align__(16) unsigned char smem[64 * 65 * 2];
  const int bid = blockIdx.x;
  if (bid < 16384) {
    // ---- LN1 row
    int row = bid;
    const float* xr = x + (long)row * 768;
    float v0 = xr[threadIdx.x], v1 = xr[threadIdx.x + 256], v2 = xr[threadIdx.x + 512];
    float s = v0 + v1 + v2, s2 = v0 * v0 + v1 * v1 + v2 * v2;
#pragma unroll
    for (int m = 1; m < 64; m <<= 1) { s += __shfl_xor(s, m); s2 += __shfl_xor(s2, m); }
    float* ws1 = (float*)smem;
    float* ws2 = ws1 + 4;
    int wv_ = threadIdx.x >> 6;
    if ((threadIdx.x & 63) == 0) { ws1[wv_] = s; ws2[wv_] = s2; }
    __syncthreads();
    s = ws1[0] + ws1[1] + ws1[2] + ws1[3];
    s2 = ws2[0] + ws2[1] + ws2[2] + ws2[3];
    float mu = s * (1.0f / 768.0f);
    float var = s2 * (1.0f / 768.0f) - mu * mu;
    float rstd = rsqrtf(var + 1e-5f);
    __bf16* orow = hb + (long)row * 768;
    orow[threadIdx.x]       = (__bf16)((v0 - mu) * rstd * ln1g[threadIdx.x]       + ln1b[threadIdx.x]);
    orow[threadIdx.x + 256] = (__bf16)((v1 - mu) * rstd * ln1g[threadIdx.x + 256] + ln1b[threadIdx.x + 256]);
    orow[threadIdx.x + 512] = (__bf16)((v2 - mu) * rstd * ln1g[threadIdx.x + 512] + ln1b[threadIdx.x + 512]);
    return;
  }
  const int id = bid - 16384;
  if (id >= 1728) {  // bias blocks
    int i = (id - 1728) * 256 + threadIdx.x;
    if (i < 2304) bqkv[i] = (i < 768) ? bq[i] : (i < 1536) ? bk[i - 768] : bv[i - 1536];
    return;
  }
  const float* W;
  __bf16* Wt;
  int K, N, tn, tk;
  if (id < 432) {
    int w3 = id / 144, r = id % 144;
    W = (w3 == 0) ? wq : (w3 == 1) ? wk : wv;
    Wt = wtqkv + (long)w3 * 768 * 768;
    K = 768; N = 768; tn = r % 12; tk = r / 12;
  } else if (id < 576) {
    int r = id - 432;
    W = wo; Wt = wto; K = 768; N = 768; tn = r % 12; tk = r / 12;
  } else if (id < 1152) {
    int r = id - 576;
    W = w1; Wt = wt1; K = 768; N = 3072; tn = r % 48; tk = r / 48;
  } else {
    int r = id - 1152;
    W = w2; Wt = wt2; K = 3072; N = 768; tn = r % 12; tk = r / 12;
  }
  __bf16 (*tile)[65] = (__bf16(*)[65])smem;
  const int tn0 = tn * 64, tk0 = tk * 64;
  const int tr = threadIdx.x >> 4, tc = (threadIdx.x & 15) * 4;
#pragma unroll
  for (int p = 0; p < 4; ++p) {
    int r = p * 16 + tr;
    float4 v = *(const float4*)&W[(long)(tk0 + r) * N + tn0 + tc];
    tile[tc + 0][r] = (__bf16)v.x;
    tile[tc + 1][r] = (__bf16)v.y;
    tile[tc + 2][r] = (__bf16)v.z;
    tile[tc + 3][r] = (__bf16)v.w;
  }
  __syncthreads();
#pragma unroll
  for (int p = 0; p < 4; ++p) {
    int n = p * 16 + tr;
    bf16x4 o;
    o[0] = tile[n][tc]; o[1] = tile[n][tc + 1]; o[2] = tile[n][tc + 2]; o[3] = tile[n][tc + 3];
    *(bf16x4*)&Wt[(long)(tn0 + n) * K + tk0 + tc] = o;
  }
}

// ---- layernorm, bf16 input variant (for x2).
__global__ __launch_bounds__(256) void ln_b_kernel(const __bf16* __restrict__ x, const float* __restrict__ g,
                                                   const float* __restrict__ b, __bf16* __restrict__ out) {
  int row = blockIdx.x;
  const __bf16* xr = x + (long)row * 768;
  float v0 = (float)xr[threadIdx.x], v1 = (float)xr[threadIdx.x + 256], v2 = (float)xr[threadIdx.x + 512];
  float s = v0 + v1 + v2, s2 = v0 * v0 + v1 * v1 + v2 * v2;
#pragma unroll
  for (int m = 1; m < 64; m <<= 1) { s += __shfl_xor(s, m); s2 += __shfl_xor(s2, m); }
  __shared__ float ws1[4], ws2[4];
  int wv = threadIdx.x >> 6;
  if ((threadIdx.x & 63) == 0) { ws1[wv] = s; ws2[wv] = s2; }
  __syncthreads();
  s = ws1[0] + ws1[1] + ws1[2] + ws1[3];
  s2 = ws2[0] + ws2[1] + ws2[2] + ws2[3];
  float mu = s * (1.0f / 768.0f);
  float var = s2 * (1.0f / 768.0f) - mu * mu;
  float rstd = rsqrtf(var + 1e-5f);
  __bf16* orow = out + (long)row * 768;
  orow[threadIdx.x]       = (__bf16)((v0 - mu) * rstd * g[threadIdx.x]       + b[threadIdx.x]);
  orow[threadIdx.x + 256] = (__bf16)((v1 - mu) * rstd * g[threadIdx.x + 256] + b[threadIdx.x + 256]);
  orow[threadIdx.x + 512] = (__bf16)((v2 - mu) * rstd * g[threadIdx.x + 512] + b[threadIdx.x + 512]);
}

// ---- GEMM: m103 structure (R12/R14/R16-verified). 128x128, BK=64, 4 waves, 32KB LDS, (256,3).
// bx-major-within-XCD (R21: L2-resident panels). VGPR=80 zero-spill; do not enlarge tile (R15)
// or raise occupancy bound (R10).
template <int EPI>
__global__ __launch_bounds__(256, 3) void gemm_kernel(const __bf16* __restrict__ A, const __bf16* __restrict__ Wt,
                                                      const float* __restrict__ bias, const float* __restrict__ resf,
                                                      const __bf16* __restrict__ resb,
                                                      float* __restrict__ outf, __bf16* __restrict__ outb,
                                                      int M, int N, int K) {
  __shared__ __align__(16) __bf16 As[8192];
  __shared__ __align__(16) __bf16 Bs[8192];
  const int tid = threadIdx.x, lane = tid & 63, w = tid >> 6;
  const int wm = w >> 1, wn = w & 1, lr = lane & 15, lh = lane >> 4;
  const int gx = gridDim.x, gy = gridDim.y;
  int id = blockIdx.x + gx * blockIdx.y;
  int xcd = id & 7, slot = id >> 3;
  const int gy8 = gy >> 3;
  int bx = slot / gy8;
  int by = xcd * gy8 + slot % gy8;
  const int m0 = by * 128, n0 = bx * 128;
  const int nt = K >> 6;
  int srow[4], scol[4];
#pragma unroll
  for (int l = 0; l < 4; ++l) {
    int c = l * 256 + tid;
    srow[l] = c >> 3;
    scol[l] = ((c & 7) ^ ((c >> 3) & 7)) * 8;
  }
  const __bf16* Ag = A + (long)m0 * K;
  const __bf16* Bg = Wt + (long)n0 * K;

  f32x4 acc[4][4] = {};
  for (int t = 0; t < nt; ++t) {
    const int kb = t << 6;
    __syncthreads();
#pragma unroll
    for (int l = 0; l < 4; ++l) {
      async16(Ag + (long)srow[l] * K + kb + scol[l], &As[l * 2048 + w * 512]);
      async16(Bg + (long)srow[l] * K + kb + scol[l], &Bs[l * 2048 + w * 512]);
    }
    __syncthreads();
    bf16x8 af[4][2], bfr[4][2];
#pragma unroll
    for (int m4 = 0; m4 < 4; ++m4) {
      int row = wm * 64 + m4 * 16 + lr;
#pragma unroll
      for (int kk = 0; kk < 2; ++kk)
        af[m4][kk] = *(const bf16x8*)&As[row * 64 + ((kk * 32 + lh * 8) ^ ((row & 7) << 3))];
    }
#pragma unroll
    for (int n = 0; n < 4; ++n) {
      int row = wn * 64 + n * 16 + lr;
#pragma unroll
      for (int kk = 0; kk < 2; ++kk)
        bfr[n][kk] = *(const bf16x8*)&Bs[row * 64 + ((kk * 32 + lh * 8) ^ ((row & 7) << 3))];
    }
    __builtin_amdgcn_s_setprio(1);
#pragma unroll
    for (int m4 = 0; m4 < 4; ++m4)
#pragma unroll
      for (int n = 0; n < 4; ++n) {
        acc[m4][n] = mfma16(af[m4][0], bfr[n][0], acc[m4][n]);
        acc[m4][n] = mfma16(af[m4][1], bfr[n][1], acc[m4][n]);
      }
    __builtin_amdgcn_s_setprio(0);
  }

#pragma unroll
  for (int m = 0; m < 4; ++m)
#pragma unroll
    for (int n = 0; n < 4; ++n) {
      int col = n0 + wn * 64 + n * 16 + lr;
      float bc = bias[col];
#pragma unroll
      for (int j = 0; j < 4; ++j) {
        int row = m0 + wm * 64 + m * 16 + lh * 4 + j;
        float v = acc[m][n][j] + bc;
        if (EPI == 1) v = gelu_f(v);
        if (EPI == 3) outb[(long)row * N + col] = (__bf16)(v + resf[(long)row * N + col]);
        else if (EPI == 4) outf[(long)row * N + col] = v + (float)resb[(long)row * N + col];
        else outb[(long)row * N + col] = (__bf16)v;
      }
    }
}

// ---- flash attention on fused qkv buffer (rows x 2304). (R19-verified: 8 waves / 256 q-rows,
// K/V staged once per block, 2-barrier scheme, counted lgkmcnt(15), no-max exp2 softmax.)
__global__ __launch_bounds__(512) void attn_kernel(const __bf16* __restrict__ qkv, __bf16* __restrict__ o) {
  __shared__ __bf16 K_lds[64][72];
  __shared__ __align__(16) unsigned char Vt[8448];
  __shared__ __align__(16) unsigned char Pt[8][4224];
  const int tid = threadIdx.x;
  const int lane = tid & 63, wv = tid >> 6;
  const int lr = lane & 15, lh = lane >> 4;
  const int hb = blockIdx.x, qt = blockIdx.y;
  const int h = hb % 12, bz = hb / 12;
  const int qrow0 = bz * 1024 + qt * 256 + wv * 32;
  const int hcol = h * 64;
  const __bf16* q = qkv + hcol;
  const __bf16* k = qkv + 768 + hcol;
  const __bf16* v = qkv + 1536 + hcol;
  const float QSC = 0.18033688011112042f;  // 0.125 * log2(e)
  bf16x8 aq[2][2];
#pragma unroll
  for (int r = 0; r < 2; ++r)
#pragma unroll
    for (int kk = 0; kk < 2; ++kk) {
      bf16x8 t = *(const bf16x8*)(q + (long)(qrow0 + r * 16 + lr) * 2304 + kk * 32 + lh * 8);
#pragma unroll
      for (int e = 0; e < 8; ++e) t[e] = (__bf16)((float)t[e] * QSC);
      aq[r][kk] = t;
    }
  bf16x8 ones;
#pragma unroll
  for (int e = 0; e < 8; ++e) ones[e] = (__bf16)1.0f;
  f32x4 o_fr[2][4] = {};
  float l_s[2][4];
#pragma unroll
  for (int r = 0; r < 2; ++r)
#pragma unroll
    for (int j = 0; j < 4; ++j) l_s[r][j] = 0.0f;
  const int r0 = tid >> 3, c0 = (tid & 7) * 8;
  const unsigned vt0 = lds_off(Vt) + (lane >> 4) * 1056 + (lane & 15) * 2;
  const int Tst = (r0 >> 2) * 4 + (c0 >> 4);
  const int vb = Tst * 128 + (r0 & 3) * 32 + (c0 & 15) * 2 + (Tst >> 3) * 32;
  const unsigned pwb = lds_off(&Pt[wv][0]) + (lr >> 2) * 256 + (lr & 3) * 32 + lh * 8;
  const unsigned prb = lds_off(&Pt[wv][0]) + lh * 512 + (lh >> 1) * 32 + lr * 2;

  const __bf16* kp = k + (long)(bz * 1024 + r0) * 2304 + c0;
  const __bf16* vp = v + (long)(bz * 1024 + r0) * 2304 + c0;
  bf16x8 rK = *(const bf16x8*)kp;
  bf16x8 rV = *(const bf16x8*)vp;
  *(bf16x8*)&K_lds[r0][c0] = rK;
  *(bf16x8*)(Vt + vb) = rV;
  __syncthreads();

  for (int t = 0; t < 16; ++t) {
    bf16x8 bk[4][2];
#pragma unroll
    for (int n = 0; n < 4; ++n)
#pragma unroll
      for (int kk = 0; kk < 2; ++kk)
        bk[n][kk] = *(const bf16x8*)&K_lds[n * 16 + lr][kk * 32 + lh * 8];
    if (t < 15) {
      kp += 64 * 2304; vp += 64 * 2304;
      rK = *(const bf16x8*)kp;
      rV = *(const bf16x8*)vp;
    }
    f32x4 sf[2][4];
    __builtin_amdgcn_s_setprio(1);
#pragma unroll
    for (int r = 0; r < 2; ++r)
#pragma unroll
      for (int n = 0; n < 4; ++n) {
        f32x4 s = {0.f, 0.f, 0.f, 0.f};
        s = mfma16(aq[r][0], bk[n][0], s);
        s = mfma16(aq[r][1], bk[n][1], s);
        sf[r][n] = s;
      }
    __builtin_amdgcn_s_setprio(0);
#define PW(rr, nn)                                                                     \
    {                                                                                  \
      float e0 = __builtin_amdgcn_exp2f(sf[rr][nn][0]);                                \
      float e1 = __builtin_amdgcn_exp2f(sf[rr][nn][1]);                                \
      float e2 = __builtin_amdgcn_exp2f(sf[rr][nn][2]);                                \
      float e3 = __builtin_amdgcn_exp2f(sf[rr][nn][3]);                                \
      u32x2 d;                                                                         \
      asm("v_cvt_pk_bf16_f32 %0, %1, %2" : "=v"(d[0]) : "v"(e0), "v"(e1));             \
      asm("v_cvt_pk_bf16_f32 %0, %1, %2" : "=v"(d[1]) : "v"(e2), "v"(e3));             \
      asm volatile("ds_write_b64 %0, %1 offset:%2" ::"v"(pwb), "v"(d),                 \
                   "i"((nn)*1056 + (rr)*128) : "memory");                              \
    }
    PW(0, 0) PW(0, 1) PW(0, 2) PW(0, 3) PW(1, 0) PW(1, 1) PW(1, 2) PW(1, 3)
#undef PW
    u32x2 trv[4][2][2];
#pragma unroll
    for (int d0 = 0; d0 < 4; ++d0)
#pragma unroll
      for (int ks = 0; ks < 2; ++ks) {
        unsigned a = vt0 + ks * 4224 + d0 * 128;
        asm volatile("ds_read_b64_tr_b16 %0, %1" : "=v"(trv[d0][ks][0]) : "v"(a));
        asm volatile("ds_read_b64_tr_b16 %0, %1 offset:512" : "=v"(trv[d0][ks][1]) : "v"(a));
      }
    asm volatile("s_waitcnt lgkmcnt(15)" ::: "memory");
    __builtin_amdgcn_sched_barrier(0);
    u32x2 trp[2][2][2];
#define PR(rr, kks)                                                                     \
    asm volatile("ds_read_b64_tr_b16 %0, %1 offset:%2"                                  \
                 : "=v"(trp[rr][kks][0]) : "v"(prb), "i"((rr)*128 + (kks)*2112));       \
    asm volatile("ds_read_b64_tr_b16 %0, %1 offset:%2"                                  \
                 : "=v"(trp[rr][kks][1]) : "v"(prb), "i"((rr)*128 + (kks)*2112 + 256));
    PR(0, 0) PR(0, 1) PR(1, 0) PR(1, 1)
#undef PR
    asm volatile("s_waitcnt lgkmcnt(0)" ::: "memory");
    __builtin_amdgcn_sched_barrier(0);
    __syncthreads();
    if (t < 15) {
      *(bf16x8*)&K_lds[r0][c0] = rK;
      *(bf16x8*)(Vt + vb) = rV;
    }
    bf16x8 ap[2][2];
#pragma unroll
    for (int r = 0; r < 2; ++r)
#pragma unroll
      for (int ks = 0; ks < 2; ++ks) {
        union { u32x2 u[2]; bf16x8 v8; } pu;
        pu.u[0] = trp[r][ks][0];
        pu.u[1] = trp[r][ks][1];
        ap[r][ks] = pu.v8;
      }
    __builtin_amdgcn_s_setprio(1);
#pragma unroll
    for (int r = 0; r < 2; ++r) {
      f32x4 ls = {0.f, 0.f, 0.f, 0.f};
      ls = mfma16(ap[r][0], ones, ls);
      ls = mfma16(ap[r][1], ones, ls);
#pragma unroll
      for (int j = 0; j < 4; ++j) l_s[r][j] += ls[j];
    }
#pragma unroll
    for (int d0 = 0; d0 < 4; ++d0) {
      union { u32x2 u[2]; bf16x8 v8; } b0, b1;
      b0.u[0] = trv[d0][0][0]; b0.u[1] = trv[d0][0][1];
      b1.u[0] = trv[d0][1][0]; b1.u[1] = trv[d0][1][1];
#pragma unroll
      for (int r = 0; r < 2; ++r) {
        o_fr[r][d0] = mfma16(ap[r][0], b0.v8, o_fr[r][d0]);
        o_fr[r][d0] = mfma16(ap[r][1], b1.v8, o_fr[r][d0]);
      }
    }
    __builtin_amdgcn_s_setprio(0);
    if (t < 15) __syncthreads();
  }
#pragma unroll
  for (int r = 0; r < 2; ++r)
#pragma unroll
    for (int d = 0; d < 4; ++d)
#pragma unroll
      for (int j = 0; j < 4; ++j) {
        int row = qrow0 + r * 16 + lh * 4 + j;
        int col = hcol + d * 16 + lr;
        o[(long)row * 768 + col] = (__bf16)(o_fr[r][d][j] * (1.0f / l_s[r][j]));
      }
}

extern "C" void kernel_launch(void* const* d_in, const int* in_sizes, int n_in,
                              void* d_out, int out_size, void* d_ws, size_t ws_size,
                              hipStream_t stream) {
  const float* x    = (const float*)d_in[0];
  const float* ln1g = (const float*)d_in[1];
  const float* ln1b = (const float*)d_in[2];
  const float* wq   = (const float*)d_in[3];
  const float* bq   = (const float*)d_in[4];
  const float* wk   = (const float*)d_in[5];
  const float* bk   = (const float*)d_in[6];
  const float* wv   = (const float*)d_in[7];
  const float* bv   = (const float*)d_in[8];
  const float* wo   = (const float*)d_in[9];
  const float* bo   = (const float*)d_in[10];
  const float* ln2g = (const float*)d_in[11];
  const float* ln2b = (const float*)d_in[12];
  const float* w1   = (const float*)d_in[13];
  const float* b1   = (const float*)d_in[14];
  const float* w2   = (const float*)d_in[15];
  const float* b2   = (const float*)d_in[16];
  float* out = (float*)d_out;
  char* ws = (char*)d_ws;

  const long SD = 16384L * 768;
  const long SF = 16384L * 3072;

  __bf16* qkv = (__bf16*)(ws);                      // 16384 x 2304
  __bf16* f1  = (__bf16*)(ws);                      // aliases qkv (dead by FFN1)
  __bf16* hb  = (__bf16*)(ws + 2 * SF);             // LN1 out; later attn out
  __bf16* x2  = (__bf16*)(ws + 2 * SF + 2 * SD);    // bf16
  __bf16* h2  = (__bf16*)(ws + 2 * SF + 2 * SD + 4 * SD);
  __bf16* wtqkv = (__bf16*)(ws + 2 * SF + 2 * SD + 4 * SD + 2 * SD);  // 2304 x 768
  __bf16* wto = wtqkv + 2304L * 768;
  __bf16* wt1 = wto + 768L * 768;
  __bf16* wt2 = wt1 + 768L * 3072;
  float*  bqkv = (float*)(wt2 + 3072L * 768);

  // merged LN1 + weight prep + bias concat (independent work, one launch)
  prep_ln_kernel<<<16384 + 1737, 256, 0, stream>>>(x, ln1g, ln1b, hb,
                                                   wq, wk, wv, wo, w1, w2, bq, bk, bv,
                                                   wtqkv, wto, wt1, wt2, bqkv);

  gemm_kernel<0><<<dim3(18, 128), 256, 0, stream>>>(hb, wtqkv, bqkv, nullptr, nullptr, nullptr, qkv, 16384, 2304, 768);
  attn_kernel<<<dim3(192, 4), 512, 0, stream>>>(qkv, hb);
  gemm_kernel<3><<<dim3(6, 128), 256, 0, stream>>>(hb, wto, bo, x, nullptr, nullptr, x2, 16384, 768, 768);
  ln_b_kernel<<<16384, 256, 0, stream>>>(x2, ln2g, ln2b, h2);
  gemm_kernel<1><<<dim3(24, 128), 256, 0, stream>>>(h2, wt1, b1, nullptr, nullptr, nullptr, f1, 16384, 3072, 768);
  gemm_kernel<4><<<dim3(6, 128), 256, 0, stream>>>(f1, wt2, b2, nullptr, x2, out, nullptr, 16384, 768, 3072);
}

// Round 23
// 350.012 us; speedup vs baseline: 1.0904x; 1.0067x over previous
//
#include <hip/hip_runtime.h>
#include <hip/hip_bf16.h>
#include <math.h>

typedef __bf16 bf16x8 __attribute__((ext_vector_type(8)));
typedef __bf16 bf16x4 __attribute__((ext_vector_type(4)));
typedef float f32x4 __attribute__((ext_vector_type(4)));
typedef unsigned int u32x2 __attribute__((ext_vector_type(2)));

__device__ __forceinline__ f32x4 mfma16(bf16x8 a, bf16x8 b, f32x4 c) {
  return __builtin_amdgcn_mfma_f32_16x16x32_bf16(a, b, c, 0, 0, 0);
}

// fast tanh-form GELU via native exp2 (R13, verified)
__device__ __forceinline__ float gelu_f(float v) {
  float x2 = v * v;
  float u = v * __builtin_fmaf(0.044715f, x2, 1.0f);
  float z = __builtin_amdgcn_exp2f(2.302101862f * u);
  float r = __builtin_amdgcn_rcpf(z + 1.0f);
  return __builtin_fmaf(-v, r, v);
}

__device__ __forceinline__ void async16(const void* g, void* l) {
  __builtin_amdgcn_global_load_lds((const __attribute__((address_space(1))) unsigned int*)g,
                                   (__attribute__((address_space(3))) unsigned int*)l, 16, 0, 0);
}

__device__ __forceinline__ unsigned lds_off(const void* p) {
  return (unsigned)(unsigned long long)(const __attribute__((address_space(3))) void*)p;
}

// ---- merged prologue: LN1 (blocks [0,16384)) + ALL weight transposes + bias concat
// (blocks [16384, 16384+1737)) in ONE launch — independent work, runs concurrently.
__global__ __launch_bounds__(256) void prep_ln_kernel(
    const float* __restrict__ x, const float* __restrict__ ln1g, const float* __restrict__ ln1b,
    __bf16* __restrict__ hb,
    const float* __restrict__ wq, const float* __restrict__ wk, const float* __restrict__ wv,
    const float* __restrict__ wo, const float* __restrict__ w1, const float* __restrict__ w2,
    const float* __restrict__ bq, const float* __restrict__ bk, const float* __restrict__ bv,
    __bf16* __restrict__ wtqkv, __bf16* __restrict__ wto,
    __bf16* __restrict__ wt1, __bf16* __restrict__ wt2, float* __restrict__ bqkv) {
  __shared__ __align__(16) unsigned char smem[64 * 65 * 2];
  const int bid = blockIdx.x;
  if (bid < 16384) {
    // ---- LN1 row
    int row = bid;
    const float* xr = x + (long)row * 768;
    float v0 = xr[threadIdx.x], v1 = xr[threadIdx.x + 256], v2 = xr[threadIdx.x + 512];
    float s = v0 + v1 + v2, s2 = v0 * v0 + v1 * v1 + v2 * v2;
#pragma unroll
    for (int m = 1; m < 64; m <<= 1) { s += __shfl_xor(s, m); s2 += __shfl_xor(s2, m); }
    float* ws1 = (float*)smem;
    float* ws2 = ws1 + 4;
    int wv_ = threadIdx.x >> 6;
    if ((threadIdx.x & 63) == 0) { ws1[wv_] = s; ws2[wv_] = s2; }
    __syncthreads();
    s = ws1[0] + ws1[1] + ws1[2] + ws1[3];
    s2 = ws2[0] + ws2[1] + ws2[2] + ws2[3];
    float mu = s * (1.0f / 768.0f);
    float var = s2 * (1.0f / 768.0f) - mu * mu;
    float rstd = rsqrtf(var + 1e-5f);
    __bf16* orow = hb + (long)row * 768;
    orow[threadIdx.x]       = (__bf16)((v0 - mu) * rstd * ln1g[threadIdx.x]       + ln1b[threadIdx.x]);
    orow[threadIdx.x + 256] = (__bf16)((v1 - mu) * rstd * ln1g[threadIdx.x + 256] + ln1b[threadIdx.x + 256]);
    orow[threadIdx.x + 512] = (__bf16)((v2 - mu) * rstd * ln1g[threadIdx.x + 512] + ln1b[threadIdx.x + 512]);
    return;
  }
  const int id = bid - 16384;
  if (id >= 1728) {  // bias blocks
    int i = (id - 1728) * 256 + threadIdx.x;
    if (i < 2304) bqkv[i] = (i < 768) ? bq[i] : (i < 1536) ? bk[i - 768] : bv[i - 1536];
    return;
  }
  const float* W;
  __bf16* Wt;
  int K, N, tn, tk;
  if (id < 432) {
    int w3 = id / 144, r = id % 144;
    W = (w3 == 0) ? wq : (w3 == 1) ? wk : wv;
    Wt = wtqkv + (long)w3 * 768 * 768;
    K = 768; N = 768; tn = r % 12; tk = r / 12;
  } else if (id < 576) {
    int r = id - 432;
    W = wo; Wt = wto; K = 768; N = 768; tn = r % 12; tk = r / 12;
  } else if (id < 1152) {
    int r = id - 576;
    W = w1; Wt = wt1; K = 768; N = 3072; tn = r % 48; tk = r / 48;
  } else {
    int r = id - 1152;
    W = w2; Wt = wt2; K = 3072; N = 768; tn = r % 12; tk = r / 12;
  }
  __bf16 (*tile)[65] = (__bf16(*)[65])smem;
  const int tn0 = tn * 64, tk0 = tk * 64;
  const int tr = threadIdx.x >> 4, tc = (threadIdx.x & 15) * 4;
#pragma unroll
  for (int p = 0; p < 4; ++p) {
    int r = p * 16 + tr;
    float4 v = *(const float4*)&W[(long)(tk0 + r) * N + tn0 + tc];
    tile[tc + 0][r] = (__bf16)v.x;
    tile[tc + 1][r] = (__bf16)v.y;
    tile[tc + 2][r] = (__bf16)v.z;
    tile[tc + 3][r] = (__bf16)v.w;
  }
  __syncthreads();
#pragma unroll
  for (int p = 0; p < 4; ++p) {
    int n = p * 16 + tr;
    bf16x4 o;
    o[0] = tile[n][tc]; o[1] = tile[n][tc + 1]; o[2] = tile[n][tc + 2]; o[3] = tile[n][tc + 3];
    *(bf16x4*)&Wt[(long)(tn0 + n) * K + tk0 + tc] = o;
  }
}

// ---- layernorm, bf16 input variant (for x2).
__global__ __launch_bounds__(256) void ln_b_kernel(const __bf16* __restrict__ x, const float* __restrict__ g,
                                                   const float* __restrict__ b, __bf16* __restrict__ out) {
  int row = blockIdx.x;
  const __bf16* xr = x + (long)row * 768;
  float v0 = (float)xr[threadIdx.x], v1 = (float)xr[threadIdx.x + 256], v2 = (float)xr[threadIdx.x + 512];
  float s = v0 + v1 + v2, s2 = v0 * v0 + v1 * v1 + v2 * v2;
#pragma unroll
  for (int m = 1; m < 64; m <<= 1) { s += __shfl_xor(s, m); s2 += __shfl_xor(s2, m); }
  __shared__ float ws1[4], ws2[4];
  int wv = threadIdx.x >> 6;
  if ((threadIdx.x & 63) == 0) { ws1[wv] = s; ws2[wv] = s2; }
  __syncthreads();
  s = ws1[0] + ws1[1] + ws1[2] + ws1[3];
  s2 = ws2[0] + ws2[1] + ws2[2] + ws2[3];
  float mu = s * (1.0f / 768.0f);
  float var = s2 * (1.0f / 768.0f) - mu * mu;
  float rstd = rsqrtf(var + 1e-5f);
  __bf16* orow = out + (long)row * 768;
  orow[threadIdx.x]       = (__bf16)((v0 - mu) * rstd * g[threadIdx.x]       + b[threadIdx.x]);
  orow[threadIdx.x + 256] = (__bf16)((v1 - mu) * rstd * g[threadIdx.x + 256] + b[threadIdx.x + 256]);
  orow[threadIdx.x + 512] = (__bf16)((v2 - mu) * rstd * g[threadIdx.x + 512] + b[threadIdx.x + 512]);
}

// ---- GEMM: m103 structure (R12/R14/R16-verified). 128x128, BK=64, 4 waves, 32KB LDS, (256,3).
// bx-major-within-XCD (R21: L2-resident panels). VGPR=80 zero-spill; do not enlarge tile (R15)
// or raise occupancy bound (R10).
template <int EPI>
__global__ __launch_bounds__(256, 3) void gemm_kernel(const __bf16* __restrict__ A, const __bf16* __restrict__ Wt,
                                                      const float* __restrict__ bias, const float* __restrict__ resf,
                                                      const __bf16* __restrict__ resb,
                                                      float* __restrict__ outf, __bf16* __restrict__ outb,
                                                      int M, int N, int K) {
  __shared__ __align__(16) __bf16 As[8192];
  __shared__ __align__(16) __bf16 Bs[8192];
  const int tid = threadIdx.x, lane = tid & 63, w = tid >> 6;
  const int wm = w >> 1, wn = w & 1, lr = lane & 15, lh = lane >> 4;
  const int gx = gridDim.x, gy = gridDim.y;
  int id = blockIdx.x + gx * blockIdx.y;
  int xcd = id & 7, slot = id >> 3;
  const int gy8 = gy >> 3;
  int bx = slot / gy8;
  int by = xcd * gy8 + slot % gy8;
  const int m0 = by * 128, n0 = bx * 128;
  const int nt = K >> 6;
  int srow[4], scol[4];
#pragma unroll
  for (int l = 0; l < 4; ++l) {
    int c = l * 256 + tid;
    srow[l] = c >> 3;
    scol[l] = ((c & 7) ^ ((c >> 3) & 7)) * 8;
  }
  const __bf16* Ag = A + (long)m0 * K;
  const __bf16* Bg = Wt + (long)n0 * K;

  f32x4 acc[4][4] = {};
  for (int t = 0; t < nt; ++t) {
    const int kb = t << 6;
    __syncthreads();
#pragma unroll
    for (int l = 0; l < 4; ++l) {
      async16(Ag + (long)srow[l] * K + kb + scol[l], &As[l * 2048 + w * 512]);
      async16(Bg + (long)srow[l] * K + kb + scol[l], &Bs[l * 2048 + w * 512]);
    }
    __syncthreads();
    bf16x8 af[4][2], bfr[4][2];
#pragma unroll
    for (int m4 = 0; m4 < 4; ++m4) {
      int row = wm * 64 + m4 * 16 + lr;
#pragma unroll
      for (int kk = 0; kk < 2; ++kk)
        af[m4][kk] = *(const bf16x8*)&As[row * 64 + ((kk * 32 + lh * 8) ^ ((row & 7) << 3))];
    }
#pragma unroll
    for (int n = 0; n < 4; ++n) {
      int row = wn * 64 + n * 16 + lr;
#pragma unroll
      for (int kk = 0; kk < 2; ++kk)
        bfr[n][kk] = *(const bf16x8*)&Bs[row * 64 + ((kk * 32 + lh * 8) ^ ((row & 7) << 3))];
    }
    __builtin_amdgcn_s_setprio(1);
#pragma unroll
    for (int m4 = 0; m4 < 4; ++m4)
#pragma unroll
      for (int n = 0; n < 4; ++n) {
        acc[m4][n] = mfma16(af[m4][0], bfr[n][0], acc[m4][n]);
        acc[m4][n] = mfma16(af[m4][1], bfr[n][1], acc[m4][n]);
      }
    __builtin_amdgcn_s_setprio(0);
  }

#pragma unroll
  for (int m = 0; m < 4; ++m)
#pragma unroll
    for (int n = 0; n < 4; ++n) {
      int col = n0 + wn * 64 + n * 16 + lr;
      float bc = bias[col];
#pragma unroll
      for (int j = 0; j < 4; ++j) {
        int row = m0 + wm * 64 + m * 16 + lh * 4 + j;
        float v = acc[m][n][j] + bc;
        if (EPI == 1) v = gelu_f(v);
        if (EPI == 3) outb[(long)row * N + col] = (__bf16)(v + resf[(long)row * N + col]);
        else if (EPI == 4) outf[(long)row * N + col] = v + (float)resb[(long)row * N + col];
        else outb[(long)row * N + col] = (__bf16)v;
      }
    }
}

// ---- flash attention on fused qkv buffer (rows x 2304). (R19-verified: 8 waves / 256 q-rows,
// K/V staged once per block, 2-barrier scheme, counted lgkmcnt(15), no-max exp2 softmax.)
__global__ __launch_bounds__(512) void attn_kernel(const __bf16* __restrict__ qkv, __bf16* __restrict__ o) {
  __shared__ __bf16 K_lds[64][72];
  __shared__ __align__(16) unsigned char Vt[8448];
  __shared__ __align__(16) unsigned char Pt[8][4224];
  const int tid = threadIdx.x;
  const int lane = tid & 63, wv = tid >> 6;
  const int lr = lane & 15, lh = lane >> 4;
  const int hb = blockIdx.x, qt = blockIdx.y;
  const int h = hb % 12, bz = hb / 12;
  const int qrow0 = bz * 1024 + qt * 256 + wv * 32;
  const int hcol = h * 64;
  const __bf16* q = qkv + hcol;
  const __bf16* k = qkv + 768 + hcol;
  const __bf16* v = qkv + 1536 + hcol;
  const float QSC = 0.18033688011112042f;  // 0.125 * log2(e)
  bf16x8 aq[2][2];
#pragma unroll
  for (int r = 0; r < 2; ++r)
#pragma unroll
    for (int kk = 0; kk < 2; ++kk) {
      bf16x8 t = *(const bf16x8*)(q + (long)(qrow0 + r * 16 + lr) * 2304 + kk * 32 + lh * 8);
#pragma unroll
      for (int e = 0; e < 8; ++e) t[e] = (__bf16)((float)t[e] * QSC);
      aq[r][kk] = t;
    }
  bf16x8 ones;
#pragma unroll
  for (int e = 0; e < 8; ++e) ones[e] = (__bf16)1.0f;
  f32x4 o_fr[2][4] = {};
  float l_s[2][4];
#pragma unroll
  for (int r = 0; r < 2; ++r)
#pragma unroll
    for (int j = 0; j < 4; ++j) l_s[r][j] = 0.0f;
  const int r0 = tid >> 3, c0 = (tid & 7) * 8;
  const unsigned vt0 = lds_off(Vt) + (lane >> 4) * 1056 + (lane & 15) * 2;
  const int Tst = (r0 >> 2) * 4 + (c0 >> 4);
  const int vb = Tst * 128 + (r0 & 3) * 32 + (c0 & 15) * 2 + (Tst >> 3) * 32;
  const unsigned pwb = lds_off(&Pt[wv][0]) + (lr >> 2) * 256 + (lr & 3) * 32 + lh * 8;
  const unsigned prb = lds_off(&Pt[wv][0]) + lh * 512 + (lh >> 1) * 32 + lr * 2;

  const __bf16* kp = k + (long)(bz * 1024 + r0) * 2304 + c0;
  const __bf16* vp = v + (long)(bz * 1024 + r0) * 2304 + c0;
  bf16x8 rK = *(const bf16x8*)kp;
  bf16x8 rV = *(const bf16x8*)vp;
  *(bf16x8*)&K_lds[r0][c0] = rK;
  *(bf16x8*)(Vt + vb) = rV;
  __syncthreads();

  for (int t = 0; t < 16; ++t) {
    bf16x8 bk[4][2];
#pragma unroll
    for (int n = 0; n < 4; ++n)
#pragma unroll
      for (int kk = 0; kk < 2; ++kk)
        bk[n][kk] = *(const bf16x8*)&K_lds[n * 16 + lr][kk * 32 + lh * 8];
    if (t < 15) {
      kp += 64 * 2304; vp += 64 * 2304;
      rK = *(const bf16x8*)kp;
      rV = *(const bf16x8*)vp;
    }
    f32x4 sf[2][4];
    __builtin_amdgcn_s_setprio(1);
#pragma unroll
    for (int r = 0; r < 2; ++r)
#pragma unroll
      for (int n = 0; n < 4; ++n) {
        f32x4 s = {0.f, 0.f, 0.f, 0.f};
        s = mfma16(aq[r][0], bk[n][0], s);
        s = mfma16(aq[r][1], bk[n][1], s);
        sf[r][n] = s;
      }
    __builtin_amdgcn_s_setprio(0);
#define PW(rr, nn)                                                                     \
    {                                                                                  \
      float e0 = __builtin_amdgcn_exp2f(sf[rr][nn][0]);                                \
      float e1 = __builtin_amdgcn_exp2f(sf[rr][nn][1]);                                \
      float e2 = __builtin_amdgcn_exp2f(sf[rr][nn][2]);                                \
      float e3 = __builtin_amdgcn_exp2f(sf[rr][nn][3]);                                \
      u32x2 d;                                                                         \
      asm("v_cvt_pk_bf16_f32 %0, %1, %2" : "=v"(d[0]) : "v"(e0), "v"(e1));             \
      asm("v_cvt_pk_bf16_f32 %0, %1, %2" : "=v"(d[1]) : "v"(e2), "v"(e3));             \
      asm volatile("ds_write_b64 %0, %1 offset:%2" ::"v"(pwb), "v"(d),                 \
                   "i"((nn)*1056 + (rr)*128) : "memory");                              \
    }
    PW(0, 0) PW(0, 1) PW(0, 2) PW(0, 3) PW(1, 0) PW(1, 1) PW(1, 2) PW(1, 3)
#undef PW
    u32x2 trv[4][2][2];
#pragma unroll
    for (int d0 = 0; d0 < 4; ++d0)
#pragma unroll
      for (int ks = 0; ks < 2; ++ks) {
        unsigned a = vt0 + ks * 4224 + d0 * 128;
        asm volatile("ds_read_b64_tr_b16 %0, %1" : "=v"(trv[d0][ks][0]) : "v"(a));
        asm volatile("ds_read_b64_tr_b16 %0, %1 offset:512" : "=v"(trv[d0][ks][1]) : "v"(a));
      }
    asm volatile("s_waitcnt lgkmcnt(15)" ::: "memory");
    __builtin_amdgcn_sched_barrier(0);
    u32x2 trp[2][2][2];
#define PR(rr, kks)                                                                     \
    asm volatile("ds_read_b64_tr_b16 %0, %1 offset:%2"                                  \
                 : "=v"(trp[rr][kks][0]) : "v"(prb), "i"((rr)*128 + (kks)*2112));       \
    asm volatile("ds_read_b64_tr_b16 %0, %1 offset:%2"                                  \
                 : "=v"(trp[rr][kks][1]) : "v"(prb), "i"((rr)*128 + (kks)*2112 + 256));
    PR(0, 0) PR(0, 1) PR(1, 0) PR(1, 1)
#undef PR
    asm volatile("s_waitcnt lgkmcnt(0)" ::: "memory");
    __builtin_amdgcn_sched_barrier(0);
    __syncthreads();
    if (t < 15) {
      *(bf16x8*)&K_lds[r0][c0] = rK;
      *(bf16x8*)(Vt + vb) = rV;
    }
    bf16x8 ap[2][2];
#pragma unroll
    for (int r = 0; r < 2; ++r)
#pragma unroll
      for (int ks = 0; ks < 2; ++ks) {
        union { u32x2 u[2]; bf16x8 v8; } pu;
        pu.u[0] = trp[r][ks][0];
        pu.u[1] = trp[r][ks][1];
        ap[r][ks] = pu.v8;
      }
    __builtin_amdgcn_s_setprio(1);
#pragma unroll
    for (int r = 0; r < 2; ++r) {
      f32x4 ls = {0.f, 0.f, 0.f, 0.f};
      ls = mfma16(ap[r][0], ones, ls);
      ls = mfma16(ap[r][1], ones, ls);
#pragma unroll
      for (int j = 0; j < 4; ++j) l_s[r][j] += ls[j];
    }
#pragma unroll
    for (int d0 = 0; d0 < 4; ++d0) {
      union { u32x2 u[2]; bf16x8 v8; } b0, b1;
      b0.u[0] = trv[d0][0][0]; b0.u[1] = trv[d0][0][1];
      b1.u[0] = trv[d0][1][0]; b1.u[1] = trv[d0][1][1];
#pragma unroll
      for (int r = 0; r < 2; ++r) {
        o_fr[r][d0] = mfma16(ap[r][0], b0.v8, o_fr[r][d0]);
        o_fr[r][d0] = mfma16(ap[r][1], b1.v8, o_fr[r][d0]);
      }
    }
    __builtin_amdgcn_s_setprio(0);
    if (t < 15) __syncthreads();
  }
#pragma unroll
  for (int r = 0; r < 2; ++r)
#pragma unroll
    for (int d = 0; d < 4; ++d)
#pragma unroll
      for (int j = 0; j < 4; ++j) {
        int row = qrow0 + r * 16 + lh * 4 + j;
        int col = hcol + d * 16 + lr;
        o[(long)row * 768 + col] = (__bf16)(o_fr[r][d][j] * (1.0f / l_s[r][j]));
      }
}

extern "C" void kernel_launch(void* const* d_in, const int* in_sizes, int n_in,
                              void* d_out, int out_size, void* d_ws, size_t ws_size,
                              hipStream_t stream) {
  const float* x    = (const float*)d_in[0];
  const float* ln1g = (const float*)d_in[1];
  const float* ln1b = (const float*)d_in[2];
  const float* wq   = (const float*)d_in[3];
  const float* bq   = (const float*)d_in[4];
  const float* wk   = (const float*)d_in[5];
  const float* bk   = (const float*)d_in[6];
  const float* wv   = (const float*)d_in[7];
  const float* bv   = (const float*)d_in[8];
  const float* wo   = (const float*)d_in[9];
  const float* bo   = (const float*)d_in[10];
  const float* ln2g = (const float*)d_in[11];
  const float* ln2b = (const float*)d_in[12];
  const float* w1   = (const float*)d_in[13];
  const float* b1   = (const float*)d_in[14];
  const float* w2   = (const float*)d_in[15];
  const float* b2   = (const float*)d_in[16];
  float* out = (float*)d_out;
  char* ws = (char*)d_ws;

  const long SD = 16384L * 768;
  const long SF = 16384L * 3072;

  __bf16* qkv = (__bf16*)(ws);                      // 16384 x 2304
  __bf16* f1  = (__bf16*)(ws);                      // aliases qkv (dead by FFN1)
  __bf16* hb  = (__bf16*)(ws + 2 * SF);             // LN1 out; later attn out
  __bf16* x2  = (__bf16*)(ws + 2 * SF + 2 * SD);    // bf16
  __bf16* h2  = (__bf16*)(ws + 2 * SF + 2 * SD + 4 * SD);
  __bf16* wtqkv = (__bf16*)(ws + 2 * SF + 2 * SD + 4 * SD + 2 * SD);  // 2304 x 768
  __bf16* wto = wtqkv + 2304L * 768;
  __bf16* wt1 = wto + 768L * 768;
  __bf16* wt2 = wt1 + 768L * 3072;
  float*  bqkv = (float*)(wt2 + 3072L * 768);

  // merged LN1 + weight prep + bias concat (independent work, one launch)
  prep_ln_kernel<<<16384 + 1737, 256, 0, stream>>>(x, ln1g, ln1b, hb,
                                                   wq, wk, wv, wo, w1, w2, bq, bk, bv,
                                                   wtqkv, wto, wt1, wt2, bqkv);

  gemm_kernel<0><<<dim3(18, 128), 256, 0, stream>>>(hb, wtqkv, bqkv, nullptr, nullptr, nullptr, qkv, 16384, 2304, 768);
  attn_kernel<<<dim3(192, 4), 512, 0, stream>>>(qkv, hb);
  gemm_kernel<3><<<dim3(6, 128), 256, 0, stream>>>(hb, wto, bo, x, nullptr, nullptr, x2, 16384, 768, 768);
  ln_b_kernel<<<16384, 256, 0, stream>>>(x2, ln2g, ln2b, h2);
  gemm_kernel<1><<<dim3(24, 128), 256, 0, stream>>>(h2, wt1, b1, nullptr, nullptr, nullptr, f1, 16384, 3072, 768);
  gemm_kernel<4><<<dim3(6, 128), 256, 0, stream>>>(f1, wt2, b2, nullptr, x2, out, nullptr, 16384, 768, 3072);
}